// Round 3
// baseline (502.337 us; speedup 1.0000x reference)
//
#include <hip/hip_runtime.h>

typedef unsigned short u16;
typedef unsigned int u32;
typedef unsigned long long u64;

#define N_NODES 100000
#define N_EDGES 1600000
#define TPITCH 136   // LDS pitch (u16): 272B rows, 16B-aligned
#define NBIN 196     // ceil(N_NODES/512)
#define BCAP 12288   // per-bin pair capacity
#define NPART 512    // radix partition blocks
#define EPB 3125     // edges per partition

typedef __bf16 bf16x8 __attribute__((ext_vector_type(8)));
typedef float  f32x4  __attribute__((ext_vector_type(4)));

__device__ inline float b2f(u16 b) { return __uint_as_float(((u32)b) << 16); }
__device__ inline float b2f_lo(u32 u) { return __uint_as_float(u << 16); }
__device__ inline float b2f_hi(u32 u) { return __uint_as_float(u & 0xffff0000u); }
__device__ inline u16 f2b(float f) {  // RNE float->bf16
    u32 u = __float_as_uint(f);
    return (u16)((u + 0x7fffu + ((u >> 16) & 1u)) >> 16);
}

__device__ inline bf16x8 ldfrag(const u16* base, int row, int k) {
    union { uint4 u; bf16x8 v; } t;
    t.u = *(const uint4*)(base + (size_t)row * 128 + k);
    return t.v;
}
__device__ inline bf16x8 ldfrag_f32(const float* base, int row, int k) {
    const float4* p = (const float4*)(base + (size_t)row * 128 + k);
    float4 a = p[0], b = p[1];
    union { u16 h[8]; bf16x8 v; } t;
    t.h[0] = f2b(a.x); t.h[1] = f2b(a.y); t.h[2] = f2b(a.z); t.h[3] = f2b(a.w);
    t.h[4] = f2b(b.x); t.h[5] = f2b(b.y); t.h[6] = f2b(b.z); t.h[7] = f2b(b.w);
    return t.v;
}
__device__ inline bf16x8 ldfrag_lds(const u16* tile, int lrow, int k) {
    union { uint4 u; bf16x8 v; } t;
    t.u = *(const uint4*)(tile + lrow * TPITCH + k);
    return t.v;
}
__device__ inline f32x4 mfma16(bf16x8 a, bf16x8 b, f32x4 c) {
    return __builtin_amdgcn_mfma_f32_16x16x32_bf16(a, b, c, 0, 0, 0);
}

// cooperative stage: 128x128 bf16 = 2048 16B chunks; 256 thr x 8 iters
__device__ inline void stage_w(const u16* __restrict__ g, u16* lds) {
    int t = threadIdx.x;
#pragma unroll
    for (int i = 0; i < 8; i++) {
        int u = t + i * 256;
        int row = u >> 4, k = (u & 15) * 8;
        *(uint4*)(lds + row * TPITCH + k) = *(const uint4*)(g + row * 128 + k);
    }
}

// ---- diagnostic ----
__global__ __launch_bounds__(256) void k_diag(u16* __restrict__ out, float val) {
    int i = blockIdx.x * 256 + threadIdx.x;
    if (i < N_NODES) out[i] = f2b(val);
}

// ---- combined detect ----
__global__ __launch_bounds__(256) void k_detects(const u64* __restrict__ e,
                                                 const u32* __restrict__ x,
                                                 int* __restrict__ flags) {
    int t = threadIdx.x;
    if (blockIdx.x == 0) {
        u64 v = 0;
#pragma unroll
        for (int i = 0; i < 4; i++) v |= e[t + 256 * i];
        if (v >> 32) atomicOr(&flags[0], 1);
    } else {
        int bad = 0;
#pragma unroll
        for (int i = 0; i < 4; i++) {
            u32 w = x[t + 256 * i];
            u32 ex = (w >> 7) & 0xff;
            if (ex < 100 || ex > 140) bad = 1;
        }
        if (bad) atomicOr(&flags[1], 1);
    }
}

__device__ inline void load_edge(const int* ei, int is32, int e, int& src, int& dst) {
    if (is32) {
        src = ei[e]; dst = ei[N_EDGES + e];
    } else {
        const long long* e64 = (const long long*)ei;
        src = (int)e64[e]; dst = (int)e64[N_EDGES + e];
    }
}

// ---- radix partition build (proven R9/R11) ----
__global__ __launch_bounds__(256) void k_rhist(const int* __restrict__ ei,
                                               int* __restrict__ ghist,
                                               const int* __restrict__ flags) {
    __shared__ int hist[NBIN];
    int p = blockIdx.x, t = threadIdx.x;
    for (int i = t; i < NBIN; i += 256) hist[i] = 0;
    __syncthreads();
    int is32 = flags[0];
    int base = p * EPB;
    int end = base + EPB; if (end > N_EDGES) end = N_EDGES;
    for (int e = base + t; e < end; e += 256) {
        int src, dst; load_edge(ei, is32, e, src, dst);
        if ((u32)src < N_NODES && (u32)dst < N_NODES) atomicAdd(&hist[dst >> 9], 1);
    }
    __syncthreads();
    for (int i = t; i < NBIN; i += 256) ghist[i * NPART + p] = hist[i];
}
__global__ __launch_bounds__(512) void k_rscan(const int* __restrict__ ghist,
                                               int* __restrict__ gbase,
                                               int* __restrict__ gcur) {
    __shared__ int buf[NPART];
    int b = blockIdx.x, t = threadIdx.x;
    int v = ghist[b * NPART + t];
    buf[t] = v;
    __syncthreads();
    for (int s = 1; s < NPART; s <<= 1) {
        int a = (t >= s) ? buf[t - s] : 0;
        __syncthreads();
        buf[t] += a;
        __syncthreads();
    }
    gbase[b * NPART + t] = buf[t] - v;
    if (t == NPART - 1) gcur[b] = buf[t];
}
__global__ __launch_bounds__(256) void k_rscatter(const int* __restrict__ ei,
                                                  const int* __restrict__ gbase,
                                                  u32* __restrict__ gbuf,
                                                  const int* __restrict__ flags) {
    __shared__ int cur[NBIN];
    int p = blockIdx.x, t = threadIdx.x;
    for (int i = t; i < NBIN; i += 256) cur[i] = gbase[i * NPART + p];
    __syncthreads();
    int is32 = flags[0];
    int base = p * EPB;
    int end = base + EPB; if (end > N_EDGES) end = N_EDGES;
    for (int e = base + t; e < end; e += 256) {
        int src, dst; load_edge(ei, is32, e, src, dst);
        if ((u32)src < N_NODES && (u32)dst < N_NODES) {
            int bin = dst >> 9;
            int pos = atomicAdd(&cur[bin], 1);
            if (pos < BCAP)
                gbuf[(size_t)bin * BCAP + pos] = ((u32)(dst & 511) << 17) | (u32)src;
        }
    }
}
__global__ __launch_bounds__(512) void k_binB(const int* __restrict__ gcur,
                                              const u32* __restrict__ gbuf,
                                              u32* __restrict__ csr,
                                              int* __restrict__ cnt,
                                              int* __restrict__ offN) {
    __shared__ int hist[512];
    __shared__ int pfx[512];
    __shared__ int cur[512];
    __shared__ u32 srcbuf[BCAP];
    int b = blockIdx.x, t = threadIdx.x;
    int n = gcur[b]; if (n > BCAP) n = BCAP;
    hist[t] = 0;
    __syncthreads();
    for (int i = t; i < n; i += 512)
        atomicAdd(&hist[gbuf[(size_t)b * BCAP + i] >> 17], 1);
    __syncthreads();
    pfx[t] = hist[t];
    __syncthreads();
    for (int s = 1; s < 512; s <<= 1) {
        int a = (t >= s) ? pfx[t - s] : 0;
        __syncthreads();
        pfx[t] += a;
        __syncthreads();
    }
    int excl = pfx[t] - hist[t];
    cur[t] = excl;
    __syncthreads();
    for (int i = t; i < n; i += 512) {
        u32 p = gbuf[(size_t)b * BCAP + i];
        int pos = atomicAdd(&cur[p >> 17], 1);
        if (pos < BCAP) srcbuf[pos] = p & 0x1FFFFu;
    }
    __syncthreads();
    int total = pfx[511];
    for (int i = t; i < total; i += 512)
        csr[(size_t)b * BCAP + i] = srcbuf[i];
    int node = b * 512 + t;
    if (node < N_NODES) {
        cnt[node] = hist[t];
        offN[node] = b * BCAP + excl;
    }
}

// ---- weight normalization -> bf16 ----
#define WTOT 99073
struct CvtArgs { const void* src[10]; int off[10]; int n[10]; };
__global__ __launch_bounds__(256) void k_cvtw(CvtArgs a, u16* __restrict__ dst,
                                              const int* __restrict__ flags) {
    int i = blockIdx.x * 256 + threadIdx.x;
    if (i >= WTOT) return;
    int isf = flags[1];
    int s = 0;
    while (s < 9 && i >= a.off[s + 1]) s++;
    int j = i - a.off[s];
    float v = isf ? ((const float*)a.src[s])[j] : b2f(((const u16*)a.src[s])[j]);
    dst[i] = f2b(v);
}
#define W_W1L 0
#define W_W1R 16384
#define W_W2L 32768
#define W_W2R 49152
#define W_W3  65536
#define W_W4  98304
#define W_B1  98560
#define W_B2  98688
#define W_B3  98816
#define W_B4  99072

// ---- x -> bf16 convert ----
__global__ __launch_bounds__(256) void k_cvtx(const void* __restrict__ x,
                                              u16* __restrict__ xb,
                                              const int* __restrict__ flags) {
    int i = blockIdx.x * 256 + threadIdx.x;
    if ((size_t)i * 4 >= (size_t)N_NODES * 128) return;
    if (flags[1]) {
        float4 v = ((const float4*)x)[i];
        union { u16 h[4]; u64 q; } t;
        t.h[0] = f2b(v.x); t.h[1] = f2b(v.y); t.h[2] = f2b(v.z); t.h[3] = f2b(v.w);
        ((u64*)xb)[i] = t.q;
    } else {
        ((u64*)xb)[i] = ((const u64*)x)[i];
    }
}

// ---- proven gather body (R0): one wave, one node, 8-deep ILP ----
// Writes packed bf16 pair per lane either to global row or LDS tile row.
__device__ inline u32 agg_node_pack(const u16* __restrict__ feat,
                                    const u32* __restrict__ csr,
                                    int s, int deg, int lane) {
    const u32* f = (const u32*)feat;
    float a0 = 0, a1 = 0, b0 = 0, b1 = 0, c0 = 0, c1 = 0, d0 = 0, d1 = 0;
    float e0 = 0, e1 = 0, g0 = 0, g1 = 0, h0f = 0, h1f = 0, i0 = 0, i1 = 0;
    int p = 0;
    for (; p + 7 < deg; p += 8) {
        u32 n0 = csr[s + p],     n1 = csr[s + p + 1], n2 = csr[s + p + 2], n3 = csr[s + p + 3];
        u32 n4 = csr[s + p + 4], n5 = csr[s + p + 5], n6 = csr[s + p + 6], n7 = csr[s + p + 7];
        if (n0 >= N_NODES) n0 = 0;
        if (n1 >= N_NODES) n1 = 0;
        if (n2 >= N_NODES) n2 = 0;
        if (n3 >= N_NODES) n3 = 0;
        if (n4 >= N_NODES) n4 = 0;
        if (n5 >= N_NODES) n5 = 0;
        if (n6 >= N_NODES) n6 = 0;
        if (n7 >= N_NODES) n7 = 0;
        u32 w0 = f[(size_t)n0 * 64 + lane];
        u32 w1 = f[(size_t)n1 * 64 + lane];
        u32 w2 = f[(size_t)n2 * 64 + lane];
        u32 w3 = f[(size_t)n3 * 64 + lane];
        u32 w4 = f[(size_t)n4 * 64 + lane];
        u32 w5 = f[(size_t)n5 * 64 + lane];
        u32 w6 = f[(size_t)n6 * 64 + lane];
        u32 w7 = f[(size_t)n7 * 64 + lane];
        a0 += b2f_lo(w0); a1 += b2f_hi(w0);
        b0 += b2f_lo(w1); b1 += b2f_hi(w1);
        c0 += b2f_lo(w2); c1 += b2f_hi(w2);
        d0 += b2f_lo(w3); d1 += b2f_hi(w3);
        e0 += b2f_lo(w4); e1 += b2f_hi(w4);
        g0 += b2f_lo(w5); g1 += b2f_hi(w5);
        h0f += b2f_lo(w6); h1f += b2f_hi(w6);
        i0 += b2f_lo(w7); i1 += b2f_hi(w7);
    }
    for (; p + 3 < deg; p += 4) {
        u32 n0 = csr[s + p], n1 = csr[s + p + 1], n2 = csr[s + p + 2], n3 = csr[s + p + 3];
        if (n0 >= N_NODES) n0 = 0;
        if (n1 >= N_NODES) n1 = 0;
        if (n2 >= N_NODES) n2 = 0;
        if (n3 >= N_NODES) n3 = 0;
        u32 w0 = f[(size_t)n0 * 64 + lane];
        u32 w1 = f[(size_t)n1 * 64 + lane];
        u32 w2 = f[(size_t)n2 * 64 + lane];
        u32 w3 = f[(size_t)n3 * 64 + lane];
        a0 += b2f_lo(w0); a1 += b2f_hi(w0);
        b0 += b2f_lo(w1); b1 += b2f_hi(w1);
        c0 += b2f_lo(w2); c1 += b2f_hi(w2);
        d0 += b2f_lo(w3); d1 += b2f_hi(w3);
    }
    for (; p < deg; p++) {
        u32 n0 = csr[s + p];
        if (n0 >= N_NODES) n0 = 0;
        u32 w0 = f[(size_t)n0 * 64 + lane];
        a0 += b2f_lo(w0); a1 += b2f_hi(w0);
    }
    float s0 = ((a0 + b0) + (c0 + d0)) + ((e0 + g0) + (h0f + i0));
    float s1 = ((a1 + b1) + (c1 + d1)) + ((e1 + g1) + (h1f + i1));
    float sc = deg > 0 ? 1.f / (float)deg : 0.f;
    u16 o0 = f2b(s0 * sc), o1 = f2b(s1 * sc);
    return (u32)o0 | ((u32)o1 << 16);
}

// ---- compact-CSR agg, bf16 features (R0 proven; used by T1 pass 2) ----
__global__ __launch_bounds__(256) void k_aggc(const u16* __restrict__ feat,
                                              const int* __restrict__ cnt,
                                              const int* __restrict__ offN,
                                              const u32* __restrict__ csr,
                                              u16* __restrict__ outb) {
    int node = blockIdx.x * 4 + (threadIdx.x >> 6);
    if (node >= N_NODES) return;
    int lane = threadIdx.x & 63;
    u32 pk = agg_node_pack(feat, csr, offN[node], cnt[node], lane);
    ((u32*)outb)[(size_t)node * 64 + lane] = pk;
}

// ---- compact-CSR agg, dual-dtype raw x (T1) ----
__global__ __launch_bounds__(256) void k_aggcx(const void* __restrict__ x,
                                               const int* __restrict__ cnt,
                                               const int* __restrict__ offN,
                                               const u32* __restrict__ csr,
                                               const int* __restrict__ flags,
                                               u16* __restrict__ outb) {
    int node = blockIdx.x * 4 + (threadIdx.x >> 6);
    if (node >= N_NODES) return;
    int lane = threadIdx.x & 63;
    int deg = cnt[node];
    int s = offN[node];
    float a0 = 0, a1 = 0, b0 = 0, b1 = 0;
    int p = 0;
    if (flags[1]) {
        const float2* f = (const float2*)x;
        for (; p + 1 < deg; p += 2) {
            u32 n0 = csr[s + p], n1 = csr[s + p + 1];
            if (n0 >= N_NODES) n0 = 0;
            if (n1 >= N_NODES) n1 = 0;
            float2 w0 = f[(size_t)n0 * 64 + lane];
            float2 w1 = f[(size_t)n1 * 64 + lane];
            a0 += w0.x; a1 += w0.y; b0 += w1.x; b1 += w1.y;
        }
        for (; p < deg; p++) {
            u32 n0 = csr[s + p];
            if (n0 >= N_NODES) n0 = 0;
            float2 w0 = f[(size_t)n0 * 64 + lane];
            a0 += w0.x; a1 += w0.y;
        }
    } else {
        const u32* f = (const u32*)x;
        for (; p + 1 < deg; p += 2) {
            u32 n0 = csr[s + p], n1 = csr[s + p + 1];
            if (n0 >= N_NODES) n0 = 0;
            if (n1 >= N_NODES) n1 = 0;
            u32 w0 = f[(size_t)n0 * 64 + lane];
            u32 w1 = f[(size_t)n1 * 64 + lane];
            a0 += b2f_lo(w0); a1 += b2f_hi(w0);
            b0 += b2f_lo(w1); b1 += b2f_hi(w1);
        }
        for (; p < deg; p++) {
            u32 n0 = csr[s + p];
            if (n0 >= N_NODES) n0 = 0;
            u32 w0 = f[(size_t)n0 * 64 + lane];
            a0 += b2f_lo(w0); a1 += b2f_hi(w0);
        }
    }
    float s0 = a0 + b0, s1 = a1 + b1;
    float sc = deg > 0 ? 1.f / (float)deg : 0.f;
    u16 o0 = f2b(s0 * sc), o1 = f2b(s1 * sc);
    ((u32*)outb)[(size_t)node * 64 + lane] = (u32)o0 | ((u32)o1 << 16);
}

// ---- R2 fused agg+conv1 (T0): 64 rows/block, wave-private LDS tile,
// weights direct from L2 (small-tier proven pattern), no barriers ----
__global__ __launch_bounds__(256) void k_fc1(
    const u16* __restrict__ xb, const int* __restrict__ cnt,
    const int* __restrict__ offN, const u32* __restrict__ csr,
    const u16* __restrict__ Wc, u16* __restrict__ h1) {
    __shared__ __align__(16) u16 tile[64 * TPITCH];  // 17.4 KB
    int wid = threadIdx.x >> 6, lane = threadIdx.x & 63;
    int r15 = lane & 15, quad = lane >> 4;
    int rb = blockIdx.x * 64;
    // gather phase: 16 nodes per wave, proven 8-deep body
    for (int i = 0; i < 16; i++) {
        int node = rb + wid * 16 + i;
        if (node > N_NODES - 1) node = N_NODES - 1;
        u32 pk = agg_node_pack(xb, csr, offN[node], cnt[node], lane);
        ((u32*)tile)[(wid * 16 + i) * (TPITCH / 2) + lane] = pk;
    }
    // conv phase (wave-private tile rows; weights from global/L2)
    int ar = rb + wid * 16 + r15; if (ar > N_NODES - 1) ar = N_NODES - 1;
    int arl = wid * 16 + r15;
    f32x4 acc[8] = {};
#pragma unroll
    for (int ks = 0; ks < 4; ks++) {
        int ko = ks * 32 + quad * 8;
        bf16x8 ag = ldfrag_lds(tile, arl, ko);
        bf16x8 ax = ldfrag(xb, ar, ko);
#pragma unroll
        for (int ct = 0; ct < 8; ct++) {
            bf16x8 bl = ldfrag(Wc + W_W1L, ct * 16 + r15, ko);
            bf16x8 br = ldfrag(Wc + W_W1R, ct * 16 + r15, ko);
            acc[ct] = mfma16(ag, bl, acc[ct]);
            acc[ct] = mfma16(ax, br, acc[ct]);
        }
    }
#pragma unroll
    for (int ct = 0; ct < 8; ct++) {
        int col = ct * 16 + r15;
        float bb = b2f(Wc[W_B1 + col]);
#pragma unroll
        for (int r = 0; r < 4; r++) {
            int row = rb + wid * 16 + quad * 4 + r;
            if (row < N_NODES)
                h1[(size_t)row * 128 + col] = f2b(fmaxf(acc[ct][r] + bb, 0.f));
        }
    }
}

// ---- R2 fused agg+conv2+MLP (T0) ----
__global__ __launch_bounds__(256) void k_fc2(
    const u16* __restrict__ h1, const int* __restrict__ cnt,
    const int* __restrict__ offN, const u32* __restrict__ csr,
    const u16* __restrict__ Wc, const int* __restrict__ flags,
    void* __restrict__ out) {
    __shared__ __align__(16) u16 tile[64 * TPITCH];  // 17.4 KB
    int wid = threadIdx.x >> 6, lane = threadIdx.x & 63;
    int r15 = lane & 15, quad = lane >> 4;
    int rb = blockIdx.x * 64;
    for (int i = 0; i < 16; i++) {
        int node = rb + wid * 16 + i;
        if (node > N_NODES - 1) node = N_NODES - 1;
        u32 pk = agg_node_pack(h1, csr, offN[node], cnt[node], lane);
        ((u32*)tile)[(wid * 16 + i) * (TPITCH / 2) + lane] = pk;
    }
    int ar = rb + wid * 16 + r15; if (ar > N_NODES - 1) ar = N_NODES - 1;
    int arl = wid * 16 + r15;
    f32x4 acc2[8] = {};
#pragma unroll
    for (int ks = 0; ks < 4; ks++) {
        int ko = ks * 32 + quad * 8;
        bf16x8 at = ldfrag_lds(tile, arl, ko);
        bf16x8 as = ldfrag(h1, ar, ko);
#pragma unroll
        for (int ct = 0; ct < 8; ct++) {
            bf16x8 bl = ldfrag(Wc + W_W2L, ct * 16 + r15, ko);
            bf16x8 br = ldfrag(Wc + W_W2R, ct * 16 + r15, ko);
            acc2[ct] = mfma16(at, bl, acc2[ct]);
            acc2[ct] = mfma16(as, br, acc2[ct]);
        }
    }
#pragma unroll
    for (int ct = 0; ct < 8; ct++) {  // h2 -> own tile rows (at-frags already in regs)
        int col = ct * 16 + r15;
        float bb = b2f(Wc[W_B2 + col]);
#pragma unroll
        for (int r = 0; r < 4; r++) {
            int lr = wid * 16 + quad * 4 + r;
            tile[lr * TPITCH + col] = f2b(acc2[ct][r] + bb);
        }
    }
    float pr[4] = {};
    float b4f = b2f(Wc[W_B4]);
#pragma unroll
    for (int half = 0; half < 2; half++) {
        f32x4 acc3[8] = {};
#pragma unroll
        for (int ks = 0; ks < 4; ks++) {
            int ko = ks * 32 + quad * 8;
            bf16x8 a = ldfrag_lds(tile, arl, ko);
#pragma unroll
            for (int ct = 0; ct < 8; ct++) {
                bf16x8 b = ldfrag(Wc + W_W3, half * 128 + ct * 16 + r15, ko);
                acc3[ct] = mfma16(a, b, acc3[ct]);
            }
        }
#pragma unroll
        for (int ct = 0; ct < 8; ct++) {
            int col = half * 128 + ct * 16 + r15;
            float bb = b2f(Wc[W_B3 + col]);
            float w4 = b2f(Wc[W_W4 + col]);
#pragma unroll
            for (int r = 0; r < 4; r++)
                pr[r] += fmaxf(acc3[ct][r] + bb, 0.f) * w4;
        }
    }
#pragma unroll
    for (int m = 1; m < 16; m <<= 1)
#pragma unroll
        for (int r = 0; r < 4; r++)
            pr[r] += __shfl_xor(pr[r], m, 64);
    if (r15 == 0) {
        int isf = flags[1];
#pragma unroll
        for (int r = 0; r < 4; r++) {
            int row = rb + wid * 16 + quad * 4 + r;
            if (row < N_NODES) {
                float v = pr[r] + b4f;
                if (isf) ((float*)out)[row] = v;
                else     ((u16*)out)[row] = f2b(v);
            }
        }
    }
}

// ---- conv1, 64 rows/block, W1l/W1r LDS-staged sequentially (T1) ----
template <bool DUALX>
__global__ __launch_bounds__(256) void k_conv1f(
    const u16* __restrict__ aggA, const void* __restrict__ xself,
    const u16* __restrict__ Wc, const int* __restrict__ flags,
    u16* __restrict__ h1) {
    __shared__ __align__(16) u16 wbuf[128 * TPITCH];  // 34.8 KB -> 4 blocks/CU
    int wid = threadIdx.x >> 6, lane = threadIdx.x & 63;
    int r15 = lane & 15, quad = lane >> 4;
    int rb = blockIdx.x * 64;
    int ar = rb + wid * 16 + r15; if (ar > N_NODES - 1) ar = N_NODES - 1;

    bf16x8 ag[4], ax[4];
    bool isf = DUALX && flags[1];
#pragma unroll
    for (int ks = 0; ks < 4; ks++) {
        int ko = ks * 32 + quad * 8;
        ag[ks] = ldfrag(aggA, ar, ko);
        ax[ks] = isf ? ldfrag_f32((const float*)xself, ar, ko)
                     : ldfrag((const u16*)xself, ar, ko);
    }
    f32x4 acc[8] = {};
    stage_w(Wc + W_W1L, wbuf);
    __syncthreads();
#pragma unroll
    for (int ks = 0; ks < 4; ks++) {
        int ko = ks * 32 + quad * 8;
#pragma unroll
        for (int ct = 0; ct < 8; ct++)
            acc[ct] = mfma16(ag[ks], ldfrag_lds(wbuf, ct * 16 + r15, ko), acc[ct]);
    }
    __syncthreads();
    stage_w(Wc + W_W1R, wbuf);
    __syncthreads();
#pragma unroll
    for (int ks = 0; ks < 4; ks++) {
        int ko = ks * 32 + quad * 8;
#pragma unroll
        for (int ct = 0; ct < 8; ct++)
            acc[ct] = mfma16(ax[ks], ldfrag_lds(wbuf, ct * 16 + r15, ko), acc[ct]);
    }
#pragma unroll
    for (int ct = 0; ct < 8; ct++) {
        int col = ct * 16 + r15;
        float bb = b2f(Wc[W_B1 + col]);
#pragma unroll
        for (int r = 0; r < 4; r++) {
            int row = rb + wid * 16 + quad * 4 + r;
            if (row < N_NODES)
                h1[(size_t)row * 128 + col] = f2b(fmaxf(acc[ct][r] + bb, 0.f));
        }
    }
}

// ---- conv2+MLP, 64 rows/block, all weights LDS-staged (T1) ----
__global__ __launch_bounds__(256) void k_conv2f(
    const u16* __restrict__ aggH, const u16* __restrict__ h1,
    const u16* __restrict__ Wc, const int* __restrict__ flags,
    void* __restrict__ out) {
    __shared__ __align__(16) u16 wbuf[128 * TPITCH];  // 34.8 KB
    __shared__ __align__(16) u16 tile[64 * TPITCH];   // 17.4 KB -> 3 blocks/CU
    int wid = threadIdx.x >> 6, lane = threadIdx.x & 63;
    int r15 = lane & 15, quad = lane >> 4;
    int rb = blockIdx.x * 64;
    int ar = rb + wid * 16 + r15; if (ar > N_NODES - 1) ar = N_NODES - 1;
    int arl = wid * 16 + r15;

    bf16x8 at[4], as[4];
#pragma unroll
    for (int ks = 0; ks < 4; ks++) {
        int ko = ks * 32 + quad * 8;
        at[ks] = ldfrag(aggH, ar, ko);
        as[ks] = ldfrag(h1, ar, ko);
    }
    f32x4 acc2[8] = {};
    stage_w(Wc + W_W2L, wbuf);
    __syncthreads();
#pragma unroll
    for (int ks = 0; ks < 4; ks++) {
        int ko = ks * 32 + quad * 8;
#pragma unroll
        for (int ct = 0; ct < 8; ct++)
            acc2[ct] = mfma16(at[ks], ldfrag_lds(wbuf, ct * 16 + r15, ko), acc2[ct]);
    }
    __syncthreads();
    stage_w(Wc + W_W2R, wbuf);
    __syncthreads();
#pragma unroll
    for (int ks = 0; ks < 4; ks++) {
        int ko = ks * 32 + quad * 8;
#pragma unroll
        for (int ct = 0; ct < 8; ct++)
            acc2[ct] = mfma16(as[ks], ldfrag_lds(wbuf, ct * 16 + r15, ko), acc2[ct]);
    }
#pragma unroll
    for (int ct = 0; ct < 8; ct++) {  // h2 -> tile (wave-local rows; wbuf untouched)
        int col = ct * 16 + r15;
        float bb = b2f(Wc[W_B2 + col]);
#pragma unroll
        for (int r = 0; r < 4; r++) {
            int lr = wid * 16 + quad * 4 + r;
            tile[lr * TPITCH + col] = f2b(acc2[ct][r] + bb);
        }
    }
    __syncthreads();  // W2r reads done + h2 visible

    float pr[4] = {};
    float b4f = b2f(Wc[W_B4]);
#pragma unroll
    for (int half = 0; half < 2; half++) {
        stage_w(Wc + W_W3 + half * 16384, wbuf);
        __syncthreads();
        f32x4 acc3[8] = {};
#pragma unroll
        for (int ks = 0; ks < 4; ks++) {
            int ko = ks * 32 + quad * 8;
            bf16x8 a = ldfrag_lds(tile, arl, ko);
#pragma unroll
            for (int ct = 0; ct < 8; ct++)
                acc3[ct] = mfma16(a, ldfrag_lds(wbuf, ct * 16 + r15, ko), acc3[ct]);
        }
#pragma unroll
        for (int ct = 0; ct < 8; ct++) {
            int col = half * 128 + ct * 16 + r15;
            float bb = b2f(Wc[W_B3 + col]);
            float w4 = b2f(Wc[W_W4 + col]);
#pragma unroll
            for (int r = 0; r < 4; r++)
                pr[r] += fmaxf(acc3[ct][r] + bb, 0.f) * w4;
        }
        __syncthreads();  // done reading this W3 half before restage
    }
#pragma unroll
    for (int m = 1; m < 16; m <<= 1)
#pragma unroll
        for (int r = 0; r < 4; r++)
            pr[r] += __shfl_xor(pr[r], m, 64);
    if (r15 == 0) {
        int isf = flags[1];
#pragma unroll
        for (int r = 0; r < 4; r++) {
            int row = rb + wid * 16 + quad * 4 + r;
            if (row < N_NODES) {
                float v = pr[r] + b4f;
                if (isf) ((float*)out)[row] = v;
                else     ((u16*)out)[row] = f2b(v);
            }
        }
    }
}

// ============ SMALL-tier kernels (proven R5 path) ============
__global__ __launch_bounds__(256) void k_hist(const int* __restrict__ ei,
                                              int* __restrict__ cnt,
                                              const int* __restrict__ flags) {
    int e = blockIdx.x * 256 + threadIdx.x;
    if (e >= N_EDGES) return;
    int src, dst; load_edge(ei, flags[0], e, src, dst);
    if ((u32)src < N_NODES && (u32)dst < N_NODES) atomicAdd(&cnt[dst], 1);
}
__global__ __launch_bounds__(1024) void k_scan(int* __restrict__ cnt,
                                               int* __restrict__ off) {
    __shared__ int buf[1024];
    __shared__ int carry_s;
    int t = threadIdx.x;
    if (t == 0) carry_s = 0;
    __syncthreads();
    for (int base = 0; base < N_NODES; base += 1024) {
        int i = base + t;
        int v = (i < N_NODES) ? cnt[i] : 0;
        buf[t] = v;
        __syncthreads();
        for (int s = 1; s < 1024; s <<= 1) {
            int a = (t >= s) ? buf[t - s] : 0;
            __syncthreads();
            buf[t] += a;
            __syncthreads();
        }
        int carry = carry_s;
        if (i < N_NODES) {
            int excl = carry + buf[t] - v;
            off[i] = excl;
            cnt[i] = excl;
        }
        __syncthreads();
        if (t == 1023) carry_s = carry + buf[1023];
        __syncthreads();
    }
    if (t == 0) off[N_NODES] = carry_s;
}
__global__ __launch_bounds__(256) void k_csr(const int* __restrict__ ei,
                                             int* __restrict__ cursor,
                                             int* __restrict__ csr,
                                             const int* __restrict__ flags) {
    int e = blockIdx.x * 256 + threadIdx.x;
    if (e >= N_EDGES) return;
    int src, dst; load_edge(ei, flags[0], e, src, dst);
    if ((u32)src < N_NODES && (u32)dst < N_NODES) {
        int pos = atomicAdd(&cursor[dst], 1);
        if ((u32)pos < N_EDGES) csr[pos] = src;
    }
}
__device__ inline void agg_bf16(const u16* __restrict__ feat,
                                const int* __restrict__ off, const int* __restrict__ csr,
                                u16* tile, int rb, int wid, int lane) {
    const u32* f32p = (const u32*)feat;
    for (int rr = 0; rr < 32; rr++) {
        int lr = wid * 32 + rr;
        int node = rb + lr;
        float s0 = 0.f, s1 = 0.f;
        int deg = 0;
        if (node < N_NODES) {
            int s = off[node], e = off[node + 1];
            if (s < 0) s = 0;
            if (e > N_EDGES) e = N_EDGES;
            if (e < s) e = s;
            deg = e - s;
            for (int p = s; p < e; p++) {
                int nb = csr[p];
                if ((u32)nb >= N_NODES) nb = 0;
                u32 u = f32p[(size_t)nb * 64 + lane];
                s0 += b2f_lo(u); s1 += b2f_hi(u);
            }
        }
        float sc = deg > 0 ? 1.f / (float)deg : 0.f;
        u16 h0 = f2b(s0 * sc), h1 = f2b(s1 * sc);
        ((u32*)tile)[lr * (TPITCH / 2) + lane] = (u32)h0 | ((u32)h1 << 16);
    }
}
__device__ inline void agg_f32(const float* __restrict__ feat,
                               const int* __restrict__ off, const int* __restrict__ csr,
                               u16* tile, int rb, int wid, int lane) {
    const float2* fp = (const float2*)feat;
    for (int rr = 0; rr < 32; rr++) {
        int lr = wid * 32 + rr;
        int node = rb + lr;
        float s0 = 0.f, s1 = 0.f;
        int deg = 0;
        if (node < N_NODES) {
            int s = off[node], e = off[node + 1];
            if (s < 0) s = 0;
            if (e > N_EDGES) e = N_EDGES;
            if (e < s) e = s;
            deg = e - s;
            for (int p = s; p < e; p++) {
                int nb = csr[p];
                if ((u32)nb >= N_NODES) nb = 0;
                float2 v = fp[(size_t)nb * 64 + lane];
                s0 += v.x; s1 += v.y;
            }
        }
        float sc = deg > 0 ? 1.f / (float)deg : 0.f;
        u16 h0 = f2b(s0 * sc), h1 = f2b(s1 * sc);
        ((u32*)tile)[lr * (TPITCH / 2) + lane] = (u32)h0 | ((u32)h1 << 16);
    }
}
__global__ __launch_bounds__(256) void k_conv1(
    const void* __restrict__ x, const int* __restrict__ off, const int* __restrict__ csr,
    const u16* __restrict__ Wc, const int* __restrict__ flags,
    u16* __restrict__ h1) {
    __shared__ __align__(16) u16 tile[128 * TPITCH];
    int wid = threadIdx.x >> 6, lane = threadIdx.x & 63;
    int r15 = lane & 15, quad = lane >> 4;
    int rb = blockIdx.x * 128;
    int isf = flags[1];
    if (isf) agg_f32((const float*)x, off, csr, tile, rb, wid, lane);
    else     agg_bf16((const u16*)x, off, csr, tile, rb, wid, lane);
    __syncthreads();
    int ar0l = wid * 32 + r15, ar1l = ar0l + 16;
    int ar0g = rb + ar0l; if (ar0g > N_NODES - 1) ar0g = N_NODES - 1;
    int ar1g = rb + ar1l; if (ar1g > N_NODES - 1) ar1g = N_NODES - 1;
    bf16x8 ax0[4], ax1[4];
    if (isf) {
#pragma unroll
        for (int ks = 0; ks < 4; ks++) {
            int ko = ks * 32 + quad * 8;
            ax0[ks] = ldfrag_f32((const float*)x, ar0g, ko);
            ax1[ks] = ldfrag_f32((const float*)x, ar1g, ko);
        }
    } else {
#pragma unroll
        for (int ks = 0; ks < 4; ks++) {
            int ko = ks * 32 + quad * 8;
            ax0[ks] = ldfrag((const u16*)x, ar0g, ko);
            ax1[ks] = ldfrag((const u16*)x, ar1g, ko);
        }
    }
    f32x4 acc[2][8] = {};
#pragma unroll
    for (int ks = 0; ks < 4; ks++) {
        int ko = ks * 32 + quad * 8;
        bf16x8 a0t = ldfrag_lds(tile, ar0l, ko);
        bf16x8 a1t = ldfrag_lds(tile, ar1l, ko);
#pragma unroll
        for (int ct = 0; ct < 8; ct++) {
            bf16x8 bl = ldfrag(Wc + W_W1L, ct * 16 + r15, ko);
            bf16x8 br = ldfrag(Wc + W_W1R, ct * 16 + r15, ko);
            acc[0][ct] = mfma16(a0t, bl, acc[0][ct]);
            acc[0][ct] = mfma16(ax0[ks], br, acc[0][ct]);
            acc[1][ct] = mfma16(a1t, bl, acc[1][ct]);
            acc[1][ct] = mfma16(ax1[ks], br, acc[1][ct]);
        }
    }
#pragma unroll
    for (int ct = 0; ct < 8; ct++) {
        int col = ct * 16 + r15;
        float bb = b2f(Wc[W_B1 + col]);
#pragma unroll
        for (int rt = 0; rt < 2; rt++) {
#pragma unroll
            for (int r = 0; r < 4; r++) {
                int row = rb + wid * 32 + rt * 16 + quad * 4 + r;
                if (row < N_NODES)
                    h1[(size_t)row * 128 + col] = f2b(fmaxf(acc[rt][ct][r] + bb, 0.f));
            }
        }
    }
}
__global__ __launch_bounds__(256) void k_conv2mlp(
    const u16* __restrict__ h1, const int* __restrict__ off, const int* __restrict__ csr,
    const u16* __restrict__ Wc, const int* __restrict__ flags,
    void* __restrict__ out) {
    __shared__ __align__(16) u16 tile[128 * TPITCH];
    int wid = threadIdx.x >> 6, lane = threadIdx.x & 63;
    int r15 = lane & 15, quad = lane >> 4;
    int rb = blockIdx.x * 128;
    agg_bf16(h1, off, csr, tile, rb, wid, lane);
    __syncthreads();
    int ar0l = wid * 32 + r15, ar1l = ar0l + 16;
    int ar0g = rb + ar0l; if (ar0g > N_NODES - 1) ar0g = N_NODES - 1;
    int ar1g = rb + ar1l; if (ar1g > N_NODES - 1) ar1g = N_NODES - 1;
    f32x4 acc2[2][8] = {};
#pragma unroll
    for (int ks = 0; ks < 4; ks++) {
        int ko = ks * 32 + quad * 8;
        bf16x8 a0t = ldfrag_lds(tile, ar0l, ko);
        bf16x8 a1t = ldfrag_lds(tile, ar1l, ko);
        bf16x8 a0s = ldfrag(h1, ar0g, ko);
        bf16x8 a1s = ldfrag(h1, ar1g, ko);
#pragma unroll
        for (int ct = 0; ct < 8; ct++) {
            bf16x8 bl = ldfrag(Wc + W_W2L, ct * 16 + r15, ko);
            bf16x8 br = ldfrag(Wc + W_W2R, ct * 16 + r15, ko);
            acc2[0][ct] = mfma16(a0t, bl, acc2[0][ct]);
            acc2[0][ct] = mfma16(a0s, br, acc2[0][ct]);
            acc2[1][ct] = mfma16(a1t, bl, acc2[1][ct]);
            acc2[1][ct] = mfma16(a1s, br, acc2[1][ct]);
        }
    }
    __syncthreads();
#pragma unroll
    for (int ct = 0; ct < 8; ct++) {
        int col = ct * 16 + r15;
        float bb = b2f(Wc[W_B2 + col]);
#pragma unroll
        for (int rt = 0; rt < 2; rt++) {
#pragma unroll
            for (int r = 0; r < 4; r++) {
                int lr = wid * 32 + rt * 16 + quad * 4 + r;
                tile[lr * TPITCH + col] = f2b(acc2[rt][ct][r] + bb);
            }
        }
    }
    __syncthreads();
    float pr[2][4] = {};
    float b4f = b2f(Wc[W_B4]);
#pragma unroll
    for (int half = 0; half < 2; half++) {
        f32x4 acc3[2][8] = {};
#pragma unroll
        for (int ks = 0; ks < 4; ks++) {
            int ko = ks * 32 + quad * 8;
            bf16x8 a0 = ldfrag_lds(tile, ar0l, ko);
            bf16x8 a1 = ldfrag_lds(tile, ar1l, ko);
#pragma unroll
            for (int ct = 0; ct < 8; ct++) {
                bf16x8 b = ldfrag(Wc + W_W3, half * 128 + ct * 16 + r15, ko);
                acc3[0][ct] = mfma16(a0, b, acc3[0][ct]);
                acc3[1][ct] = mfma16(a1, b, acc3[1][ct]);
            }
        }
#pragma unroll
        for (int ct = 0; ct < 8; ct++) {
            int col = half * 128 + ct * 16 + r15;
            float bb = b2f(Wc[W_B3 + col]);
            float w4 = b2f(Wc[W_W4 + col]);
#pragma unroll
            for (int rt = 0; rt < 2; rt++)
#pragma unroll
                for (int r = 0; r < 4; r++)
                    pr[rt][r] += fmaxf(acc3[rt][ct][r] + bb, 0.f) * w4;
        }
    }
#pragma unroll
    for (int m = 1; m < 16; m <<= 1)
#pragma unroll
        for (int rt = 0; rt < 2; rt++)
#pragma unroll
            for (int r = 0; r < 4; r++)
                pr[rt][r] += __shfl_xor(pr[rt][r], m, 64);
    if (r15 == 0) {
        int isf = flags[1];
#pragma unroll
        for (int rt = 0; rt < 2; rt++) {
#pragma unroll
            for (int r = 0; r < 4; r++) {
                int row = rb + wid * 32 + rt * 16 + quad * 4 + r;
                if (row < N_NODES) {
                    float v = pr[rt][r] + b4f;
                    if (isf) ((float*)out)[row] = v;
                    else     ((u16*)out)[row] = f2b(v);
                }
            }
        }
    }
}

extern "C" void kernel_launch(void* const* d_in, const int* in_sizes, int n_in,
                              void* d_out, int out_size, void* d_ws, size_t ws_size,
                              hipStream_t stream) {
    const void* x  = d_in[0];
    const int* ei  = (const int*)d_in[1];

    const size_t A = 256;
    const size_t sFlg  = 256;
    const size_t sGcur = 1024;
    const size_t sGh   = (((size_t)NBIN * NPART * 4) + A - 1) & ~(A - 1);
    const size_t sCnt  = (((size_t)N_NODES * 4) + A - 1) & ~(A - 1);
    const size_t sOffN = (((size_t)N_NODES * 4) + A - 1) & ~(A - 1);
    const size_t sWc   = ((WTOT * 2) + A - 1) & ~(A - 1);
    const size_t sCsrB = (((size_t)NBIN * BCAP * 4) + A - 1) & ~(A - 1);
    const size_t sFB   = (((size_t)N_NODES * 128 * 2) + A - 1) & ~(A - 1);
    const size_t sOff  = (((size_t)(N_NODES + 1) * 4) + A - 1) & ~(A - 1);
    const size_t sCsr  = (((size_t)N_EDGES * 4) + A - 1) & ~(A - 1);
    const size_t needB1 = sFlg + sGcur + 2 * sGh + sCnt + sOffN + sWc + sCsrB + 2 * sFB;
    const size_t needB0 = needB1 + sFB;
    const size_t needS  = sFlg + sCnt + sOff + sCsr + sFB;

    char* ws = (char*)d_ws;
    int gconv = (N_NODES + 63) / 64;
    int gagg  = (N_NODES + 3) / 4;

    CvtArgs ca;
    const int srcIdx[10] = {2, 4, 5, 7, 8, 10, 3, 6, 9, 11};
    const int offs[10] = {W_W1L, W_W1R, W_W2L, W_W2R, W_W3, W_W4, W_B1, W_B2, W_B3, W_B4};
    const int ns[10]   = {16384, 16384, 16384, 16384, 32768, 256, 128, 128, 256, 1};
    for (int i = 0; i < 10; i++) { ca.src[i] = d_in[srcIdx[i]]; ca.off[i] = offs[i]; ca.n[i] = ns[i]; }

    if (ws_size >= needB1) {
        bool t0 = ws_size >= needB0;
        int* flags = (int*)ws;
        int* gcur  = (int*)(ws + sFlg);
        int* ghist = (int*)(ws + sFlg + sGcur);
        int* gbase = (int*)(ws + sFlg + sGcur + sGh);
        int* cnt   = (int*)(ws + sFlg + sGcur + 2 * sGh);
        int* offN  = (int*)(ws + sFlg + sGcur + 2 * sGh + sCnt);
        u16* Wc    = (u16*)(ws + sFlg + sGcur + 2 * sGh + sCnt + sOffN);
        u32* csrb  = (u32*)(ws + sFlg + sGcur + 2 * sGh + sCnt + sOffN + sWc);
        u16* B1    = (u16*)(ws + sFlg + sGcur + 2 * sGh + sCnt + sOffN + sWc + sCsrB);
        u16* B2    = B1 + (sFB / 2);
        u32* gbuf  = (u32*)B2;         // dead after k_binB
        u16* xb    = B2 + (sFB / 2);   // T0 only

        hipMemsetAsync(ws, 0, sFlg, stream);
        k_detects<<<2, 256, 0, stream>>>((const u64*)ei, (const u32*)x, flags);
        k_rhist<<<NPART, 256, 0, stream>>>(ei, ghist, flags);
        k_rscan<<<NBIN, 512, 0, stream>>>(ghist, gbase, gcur);
        k_rscatter<<<NPART, 256, 0, stream>>>(ei, gbase, gbuf, flags);
        k_binB<<<NBIN, 512, 0, stream>>>(gcur, gbuf, csrb, cnt, offN);
        k_cvtw<<<(WTOT + 255) / 256, 256, 0, stream>>>(ca, Wc, flags);

        if (t0) {
            k_cvtx<<<((N_NODES * 128 / 4) + 255) / 256, 256, 0, stream>>>(x, xb, flags);
            k_fc1<<<gconv, 256, 0, stream>>>(xb, cnt, offN, csrb, Wc, B2);
            k_fc2<<<gconv, 256, 0, stream>>>(B2, cnt, offN, csrb, Wc, flags, d_out);
        } else {
            k_aggcx<<<gagg, 256, 0, stream>>>(x, cnt, offN, csrb, flags, B1);
            k_conv1f<true><<<gconv, 256, 0, stream>>>(B1, x, Wc, flags, B2);
            k_aggc<<<gagg, 256, 0, stream>>>(B2, cnt, offN, csrb, B1);
            k_conv2f<<<gconv, 256, 0, stream>>>(B1, B2, Wc, flags, d_out);
        }
    } else if (ws_size >= needS) {
        int* flags = (int*)ws;
        int* cnt   = (int*)(ws + sFlg);
        u16* Wc    = (u16*)(ws + sFlg);
        int* off   = (int*)(ws + sFlg + sCnt);
        int* csr   = (int*)(ws + sFlg + sCnt + sOff);
        u16* h1    = (u16*)(ws + sFlg + sCnt + sOff + sCsr);

        hipMemsetAsync(ws, 0, sFlg + (size_t)N_NODES * 4, stream);
        k_detects<<<2, 256, 0, stream>>>((const u64*)ei, (const u32*)x, flags);
        k_hist<<<N_EDGES / 256, 256, 0, stream>>>(ei, cnt, flags);
        k_scan<<<1, 1024, 0, stream>>>(cnt, off);
        k_csr<<<N_EDGES / 256, 256, 0, stream>>>(ei, cnt, csr, flags);
        k_cvtw<<<(WTOT + 255) / 256, 256, 0, stream>>>(ca, Wc, flags);
        k_conv1<<<(N_NODES + 127) / 128, 256, 0, stream>>>(x, off, csr, Wc, flags, h1);
        k_conv2mlp<<<(N_NODES + 127) / 128, 256, 0, stream>>>(h1, off, csr, Wc, flags, d_out);
    } else {
        k_diag<<<(N_NODES + 255) / 256, 256, 0, stream>>>(
            (u16*)d_out, 2000.0f + (float)(ws_size >> 20));
    }
}

// Round 5
// 348.014 us; speedup vs baseline: 1.4434x; 1.4434x over previous
//
#include <hip/hip_runtime.h>

typedef unsigned short u16;
typedef unsigned int u32;
typedef unsigned long long u64;

#define N_NODES 100000
#define N_EDGES 1600000
#define TPITCH 136   // LDS pitch (u16): 272B rows, 16B-aligned
#define NBIN 196     // ceil(N_NODES/512)
#define BCAP 12288   // per-bin pair capacity
#define NPART 512    // radix partition blocks
#define EPB 3125     // edges per partition

typedef __bf16 bf16x8 __attribute__((ext_vector_type(8)));
typedef float  f32x4  __attribute__((ext_vector_type(4)));

__device__ inline float b2f(u16 b) { return __uint_as_float(((u32)b) << 16); }
__device__ inline float b2f_lo(u32 u) { return __uint_as_float(u << 16); }
__device__ inline float b2f_hi(u32 u) { return __uint_as_float(u & 0xffff0000u); }
__device__ inline u16 f2b(float f) {  // RNE float->bf16
    u32 u = __float_as_uint(f);
    return (u16)((u + 0x7fffu + ((u >> 16) & 1u)) >> 16);
}

__device__ inline bf16x8 ldfrag(const u16* base, int row, int k) {
    union { uint4 u; bf16x8 v; } t;
    t.u = *(const uint4*)(base + (size_t)row * 128 + k);
    return t.v;
}
__device__ inline bf16x8 ldfrag_f32(const float* base, int row, int k) {
    const float4* p = (const float4*)(base + (size_t)row * 128 + k);
    float4 a = p[0], b = p[1];
    union { u16 h[8]; bf16x8 v; } t;
    t.h[0] = f2b(a.x); t.h[1] = f2b(a.y); t.h[2] = f2b(a.z); t.h[3] = f2b(a.w);
    t.h[4] = f2b(b.x); t.h[5] = f2b(b.y); t.h[6] = f2b(b.z); t.h[7] = f2b(b.w);
    return t.v;
}
__device__ inline bf16x8 ldfrag_lds(const u16* tile, int lrow, int k) {
    union { uint4 u; bf16x8 v; } t;
    t.u = *(const uint4*)(tile + lrow * TPITCH + k);
    return t.v;
}
__device__ inline f32x4 mfma16(bf16x8 a, bf16x8 b, f32x4 c) {
    return __builtin_amdgcn_mfma_f32_16x16x32_bf16(a, b, c, 0, 0, 0);
}

// cooperative stage: 128x128 bf16 = 2048 16B chunks; 256 thr x 8 iters
__device__ inline void stage_w(const u16* __restrict__ g, u16* lds) {
    int t = threadIdx.x;
#pragma unroll
    for (int i = 0; i < 8; i++) {
        int u = t + i * 256;
        int row = u >> 4, k = (u & 15) * 8;
        *(uint4*)(lds + row * TPITCH + k) = *(const uint4*)(g + row * 128 + k);
    }
}

// ---- diagnostic ----
__global__ __launch_bounds__(256) void k_diag(u16* __restrict__ out, float val) {
    int i = blockIdx.x * 256 + threadIdx.x;
    if (i < N_NODES) out[i] = f2b(val);
}

// ---- combined detect ----
__global__ __launch_bounds__(256) void k_detects(const u64* __restrict__ e,
                                                 const u32* __restrict__ x,
                                                 int* __restrict__ flags) {
    int t = threadIdx.x;
    if (blockIdx.x == 0) {
        u64 v = 0;
#pragma unroll
        for (int i = 0; i < 4; i++) v |= e[t + 256 * i];
        if (v >> 32) atomicOr(&flags[0], 1);
    } else {
        int bad = 0;
#pragma unroll
        for (int i = 0; i < 4; i++) {
            u32 w = x[t + 256 * i];
            u32 ex = (w >> 7) & 0xff;
            if (ex < 100 || ex > 140) bad = 1;
        }
        if (bad) atomicOr(&flags[1], 1);
    }
}

__device__ inline void load_edge(const int* ei, int is32, int e, int& src, int& dst) {
    if (is32) {
        src = ei[e]; dst = ei[N_EDGES + e];
    } else {
        const long long* e64 = (const long long*)ei;
        src = (int)e64[e]; dst = (int)e64[N_EDGES + e];
    }
}

// ---- radix partition build (proven R9/R11) ----
__global__ __launch_bounds__(256) void k_rhist(const int* __restrict__ ei,
                                               int* __restrict__ ghist,
                                               const int* __restrict__ flags) {
    __shared__ int hist[NBIN];
    int p = blockIdx.x, t = threadIdx.x;
    for (int i = t; i < NBIN; i += 256) hist[i] = 0;
    __syncthreads();
    int is32 = flags[0];
    int base = p * EPB;
    int end = base + EPB; if (end > N_EDGES) end = N_EDGES;
    for (int e = base + t; e < end; e += 256) {
        int src, dst; load_edge(ei, is32, e, src, dst);
        if ((u32)src < N_NODES && (u32)dst < N_NODES) atomicAdd(&hist[dst >> 9], 1);
    }
    __syncthreads();
    for (int i = t; i < NBIN; i += 256) ghist[i * NPART + p] = hist[i];
}
__global__ __launch_bounds__(512) void k_rscan(const int* __restrict__ ghist,
                                               int* __restrict__ gbase,
                                               int* __restrict__ gcur) {
    __shared__ int buf[NPART];
    int b = blockIdx.x, t = threadIdx.x;
    int v = ghist[b * NPART + t];
    buf[t] = v;
    __syncthreads();
    for (int s = 1; s < NPART; s <<= 1) {
        int a = (t >= s) ? buf[t - s] : 0;
        __syncthreads();
        buf[t] += a;
        __syncthreads();
    }
    gbase[b * NPART + t] = buf[t] - v;
    if (t == NPART - 1) gcur[b] = buf[t];
}
__global__ __launch_bounds__(256) void k_rscatter(const int* __restrict__ ei,
                                                  const int* __restrict__ gbase,
                                                  u32* __restrict__ gbuf,
                                                  const int* __restrict__ flags) {
    __shared__ int cur[NBIN];
    int p = blockIdx.x, t = threadIdx.x;
    for (int i = t; i < NBIN; i += 256) cur[i] = gbase[i * NPART + p];
    __syncthreads();
    int is32 = flags[0];
    int base = p * EPB;
    int end = base + EPB; if (end > N_EDGES) end = N_EDGES;
    for (int e = base + t; e < end; e += 256) {
        int src, dst; load_edge(ei, is32, e, src, dst);
        if ((u32)src < N_NODES && (u32)dst < N_NODES) {
            int bin = dst >> 9;
            int pos = atomicAdd(&cur[bin], 1);
            if (pos < BCAP)
                gbuf[(size_t)bin * BCAP + pos] = ((u32)(dst & 511) << 17) | (u32)src;
        }
    }
}
__global__ __launch_bounds__(512) void k_binB(const int* __restrict__ gcur,
                                              const u32* __restrict__ gbuf,
                                              u32* __restrict__ csr,
                                              int* __restrict__ cnt,
                                              int* __restrict__ offN) {
    __shared__ int hist[512];
    __shared__ int pfx[512];
    __shared__ int cur[512];
    __shared__ u32 srcbuf[BCAP];
    int b = blockIdx.x, t = threadIdx.x;
    int n = gcur[b]; if (n > BCAP) n = BCAP;
    hist[t] = 0;
    __syncthreads();
    for (int i = t; i < n; i += 512)
        atomicAdd(&hist[gbuf[(size_t)b * BCAP + i] >> 17], 1);
    __syncthreads();
    pfx[t] = hist[t];
    __syncthreads();
    for (int s = 1; s < 512; s <<= 1) {
        int a = (t >= s) ? pfx[t - s] : 0;
        __syncthreads();
        pfx[t] += a;
        __syncthreads();
    }
    int excl = pfx[t] - hist[t];
    cur[t] = excl;
    __syncthreads();
    for (int i = t; i < n; i += 512) {
        u32 p = gbuf[(size_t)b * BCAP + i];
        int pos = atomicAdd(&cur[p >> 17], 1);
        if (pos < BCAP) srcbuf[pos] = p & 0x1FFFFu;
    }
    __syncthreads();
    int total = pfx[511];
    for (int i = t; i < total; i += 512)
        csr[(size_t)b * BCAP + i] = srcbuf[i];
    int node = b * 512 + t;
    if (node < N_NODES) {
        cnt[node] = hist[t];
        offN[node] = b * BCAP + excl;
    }
}

// ---- weight normalization -> bf16 ----
#define WTOT 99073
struct CvtArgs { const void* src[10]; int off[10]; int n[10]; };
__global__ __launch_bounds__(256) void k_cvtw(CvtArgs a, u16* __restrict__ dst,
                                              const int* __restrict__ flags) {
    int i = blockIdx.x * 256 + threadIdx.x;
    if (i >= WTOT) return;
    int isf = flags[1];
    int s = 0;
    while (s < 9 && i >= a.off[s + 1]) s++;
    int j = i - a.off[s];
    float v = isf ? ((const float*)a.src[s])[j] : b2f(((const u16*)a.src[s])[j]);
    dst[i] = f2b(v);
}
#define W_W1L 0
#define W_W1R 16384
#define W_W2L 32768
#define W_W2R 49152
#define W_W3  65536
#define W_W4  98304
#define W_B1  98560
#define W_B2  98688
#define W_B3  98816
#define W_B4  99072

// ---- x -> bf16 convert ----
__global__ __launch_bounds__(256) void k_cvtx(const void* __restrict__ x,
                                              u16* __restrict__ xb,
                                              const int* __restrict__ flags) {
    int i = blockIdx.x * 256 + threadIdx.x;
    if ((size_t)i * 4 >= (size_t)N_NODES * 128) return;
    if (flags[1]) {
        float4 v = ((const float4*)x)[i];
        union { u16 h[4]; u64 q; } t;
        t.h[0] = f2b(v.x); t.h[1] = f2b(v.y); t.h[2] = f2b(v.z); t.h[3] = f2b(v.w);
        ((u64*)xb)[i] = t.q;
    } else {
        ((u64*)xb)[i] = ((const u64*)x)[i];
    }
}

// ---- compact-CSR agg, bf16 features ----
// R3: half-wave split (lanes 0-31 even neighbors, 32-63 odd), u64 feature
// loads (one VMEM = full 256B row per half-wave), indices loaded directly
// per-half (NO shuffle chain - R2's mistake). 8-deep ILP, 16 rows in
// flight per wave. Cross-half combine via 4x shfl_xor(32) at the end.
__global__ __launch_bounds__(256) void k_aggc(const u16* __restrict__ feat,
                                              const int* __restrict__ cnt,
                                              const int* __restrict__ offN,
                                              const u32* __restrict__ csr,
                                              u16* __restrict__ outb) {
    int node = blockIdx.x * 4 + (threadIdx.x >> 6);
    if (node >= N_NODES) return;
    int lane = threadIdx.x & 63;
    int half = lane >> 5;     // 0: even-indexed neighbors, 1: odd
    int l32 = lane & 31;
    int deg = cnt[node];
    int s = offN[node];
    const u64* fq = (const u64*)feat;   // 32 u64 words per 256B row
    float a0 = 0, a1 = 0, a2 = 0, a3 = 0;
    float b0 = 0, b1 = 0, b2 = 0, b3 = 0;
    float c0 = 0, c1 = 0, c2 = 0, c3 = 0;
    float d0 = 0, d1 = 0, d2 = 0, d3 = 0;
    int p = 0;
    for (; p + 15 < deg; p += 16) {
        u32 n0 = csr[s + p +  0 + half];
        u32 n1 = csr[s + p +  2 + half];
        u32 n2 = csr[s + p +  4 + half];
        u32 n3 = csr[s + p +  6 + half];
        u32 n4 = csr[s + p +  8 + half];
        u32 n5 = csr[s + p + 10 + half];
        u32 n6 = csr[s + p + 12 + half];
        u32 n7 = csr[s + p + 14 + half];
        if (n0 >= N_NODES) n0 = 0;
        if (n1 >= N_NODES) n1 = 0;
        if (n2 >= N_NODES) n2 = 0;
        if (n3 >= N_NODES) n3 = 0;
        if (n4 >= N_NODES) n4 = 0;
        if (n5 >= N_NODES) n5 = 0;
        if (n6 >= N_NODES) n6 = 0;
        if (n7 >= N_NODES) n7 = 0;
        u64 w0 = fq[(size_t)n0 * 32 + l32];
        u64 w1 = fq[(size_t)n1 * 32 + l32];
        u64 w2 = fq[(size_t)n2 * 32 + l32];
        u64 w3 = fq[(size_t)n3 * 32 + l32];
        u64 w4 = fq[(size_t)n4 * 32 + l32];
        u64 w5 = fq[(size_t)n5 * 32 + l32];
        u64 w6 = fq[(size_t)n6 * 32 + l32];
        u64 w7 = fq[(size_t)n7 * 32 + l32];
        a0 += b2f_lo((u32)w0); a1 += b2f_hi((u32)w0);
        a2 += b2f_lo((u32)(w0 >> 32)); a3 += b2f_hi((u32)(w0 >> 32));
        b0 += b2f_lo((u32)w1); b1 += b2f_hi((u32)w1);
        b2 += b2f_lo((u32)(w1 >> 32)); b3 += b2f_hi((u32)(w1 >> 32));
        c0 += b2f_lo((u32)w2); c1 += b2f_hi((u32)w2);
        c2 += b2f_lo((u32)(w2 >> 32)); c3 += b2f_hi((u32)(w2 >> 32));
        d0 += b2f_lo((u32)w3); d1 += b2f_hi((u32)w3);
        d2 += b2f_lo((u32)(w3 >> 32)); d3 += b2f_hi((u32)(w3 >> 32));
        a0 += b2f_lo((u32)w4); a1 += b2f_hi((u32)w4);
        a2 += b2f_lo((u32)(w4 >> 32)); a3 += b2f_hi((u32)(w4 >> 32));
        b0 += b2f_lo((u32)w5); b1 += b2f_hi((u32)w5);
        b2 += b2f_lo((u32)(w5 >> 32)); b3 += b2f_hi((u32)(w5 >> 32));
        c0 += b2f_lo((u32)w6); c1 += b2f_hi((u32)w6);
        c2 += b2f_lo((u32)(w6 >> 32)); c3 += b2f_hi((u32)(w6 >> 32));
        d0 += b2f_lo((u32)w7); d1 += b2f_hi((u32)w7);
        d2 += b2f_lo((u32)(w7 >> 32)); d3 += b2f_hi((u32)(w7 >> 32));
    }
    for (; p + 1 < deg; p += 2) {
        u32 n = csr[s + p + half];
        if (n >= N_NODES) n = 0;
        u64 w = fq[(size_t)n * 32 + l32];
        a0 += b2f_lo((u32)w); a1 += b2f_hi((u32)w);
        a2 += b2f_lo((u32)(w >> 32)); a3 += b2f_hi((u32)(w >> 32));
    }
    if (p < deg) {   // odd tail: only lower half contributes
        u32 n = csr[s + p];
        if (n >= N_NODES) n = 0;
        u64 w = fq[(size_t)n * 32 + l32];
        float z = half ? 0.f : 1.f;
        a0 += z * b2f_lo((u32)w); a1 += z * b2f_hi((u32)w);
        a2 += z * b2f_lo((u32)(w >> 32)); a3 += z * b2f_hi((u32)(w >> 32));
    }
    a0 += b0 + c0 + d0; a1 += b1 + c1 + d1;
    a2 += b2 + c2 + d2; a3 += b3 + c3 + d3;
    a0 += __shfl_xor(a0, 32, 64);
    a1 += __shfl_xor(a1, 32, 64);
    a2 += __shfl_xor(a2, 32, 64);
    a3 += __shfl_xor(a3, 32, 64);
    float sc = deg > 0 ? 1.f / (float)deg : 0.f;
    if (half == 0) {
        union { u16 h[4]; u64 q; } t;
        t.h[0] = f2b(a0 * sc); t.h[1] = f2b(a1 * sc);
        t.h[2] = f2b(a2 * sc); t.h[3] = f2b(a3 * sc);
        ((u64*)outb)[(size_t)node * 32 + l32] = t.q;
    }
}

// ---- compact-CSR agg, dual-dtype raw x (T1) ----
__global__ __launch_bounds__(256) void k_aggcx(const void* __restrict__ x,
                                               const int* __restrict__ cnt,
                                               const int* __restrict__ offN,
                                               const u32* __restrict__ csr,
                                               const int* __restrict__ flags,
                                               u16* __restrict__ outb) {
    int node = blockIdx.x * 4 + (threadIdx.x >> 6);
    if (node >= N_NODES) return;
    int lane = threadIdx.x & 63;
    int deg = cnt[node];
    int s = offN[node];
    float a0 = 0, a1 = 0, b0 = 0, b1 = 0;
    int p = 0;
    if (flags[1]) {
        const float2* f = (const float2*)x;
        for (; p + 1 < deg; p += 2) {
            u32 n0 = csr[s + p], n1 = csr[s + p + 1];
            if (n0 >= N_NODES) n0 = 0;
            if (n1 >= N_NODES) n1 = 0;
            float2 w0 = f[(size_t)n0 * 64 + lane];
            float2 w1 = f[(size_t)n1 * 64 + lane];
            a0 += w0.x; a1 += w0.y; b0 += w1.x; b1 += w1.y;
        }
        for (; p < deg; p++) {
            u32 n0 = csr[s + p];
            if (n0 >= N_NODES) n0 = 0;
            float2 w0 = f[(size_t)n0 * 64 + lane];
            a0 += w0.x; a1 += w0.y;
        }
    } else {
        const u32* f = (const u32*)x;
        for (; p + 1 < deg; p += 2) {
            u32 n0 = csr[s + p], n1 = csr[s + p + 1];
            if (n0 >= N_NODES) n0 = 0;
            if (n1 >= N_NODES) n1 = 0;
            u32 w0 = f[(size_t)n0 * 64 + lane];
            u32 w1 = f[(size_t)n1 * 64 + lane];
            a0 += b2f_lo(w0); a1 += b2f_hi(w0);
            b0 += b2f_lo(w1); b1 += b2f_hi(w1);
        }
        for (; p < deg; p++) {
            u32 n0 = csr[s + p];
            if (n0 >= N_NODES) n0 = 0;
            u32 w0 = f[(size_t)n0 * 64 + lane];
            a0 += b2f_lo(w0); a1 += b2f_hi(w0);
        }
    }
    float s0 = a0 + b0, s1 = a1 + b1;
    float sc = deg > 0 ? 1.f / (float)deg : 0.f;
    u16 o0 = f2b(s0 * sc), o1 = f2b(s1 * sc);
    ((u32*)outb)[(size_t)node * 64 + lane] = (u32)o0 | ((u32)o1 << 16);
}

// ---- conv1, 64 rows/block, W1l/W1r LDS-staged sequentially ----
template <bool DUALX>
__global__ __launch_bounds__(256) void k_conv1f(
    const u16* __restrict__ aggA, const void* __restrict__ xself,
    const u16* __restrict__ Wc, const int* __restrict__ flags,
    u16* __restrict__ h1) {
    __shared__ __align__(16) u16 wbuf[128 * TPITCH];  // 34.8 KB -> 4 blocks/CU
    int wid = threadIdx.x >> 6, lane = threadIdx.x & 63;
    int r15 = lane & 15, quad = lane >> 4;
    int rb = blockIdx.x * 64;
    int ar = rb + wid * 16 + r15; if (ar > N_NODES - 1) ar = N_NODES - 1;

    bf16x8 ag[4], ax[4];
    bool isf = DUALX && flags[1];
#pragma unroll
    for (int ks = 0; ks < 4; ks++) {
        int ko = ks * 32 + quad * 8;
        ag[ks] = ldfrag(aggA, ar, ko);
        ax[ks] = isf ? ldfrag_f32((const float*)xself, ar, ko)
                     : ldfrag((const u16*)xself, ar, ko);
    }
    f32x4 acc[8] = {};
    stage_w(Wc + W_W1L, wbuf);
    __syncthreads();
#pragma unroll
    for (int ks = 0; ks < 4; ks++) {
        int ko = ks * 32 + quad * 8;
#pragma unroll
        for (int ct = 0; ct < 8; ct++)
            acc[ct] = mfma16(ag[ks], ldfrag_lds(wbuf, ct * 16 + r15, ko), acc[ct]);
    }
    __syncthreads();
    stage_w(Wc + W_W1R, wbuf);
    __syncthreads();
#pragma unroll
    for (int ks = 0; ks < 4; ks++) {
        int ko = ks * 32 + quad * 8;
#pragma unroll
        for (int ct = 0; ct < 8; ct++)
            acc[ct] = mfma16(ax[ks], ldfrag_lds(wbuf, ct * 16 + r15, ko), acc[ct]);
    }
#pragma unroll
    for (int ct = 0; ct < 8; ct++) {
        int col = ct * 16 + r15;
        float bb = b2f(Wc[W_B1 + col]);
#pragma unroll
        for (int r = 0; r < 4; r++) {
            int row = rb + wid * 16 + quad * 4 + r;
            if (row < N_NODES)
                h1[(size_t)row * 128 + col] = f2b(fmaxf(acc[ct][r] + bb, 0.f));
        }
    }
}

// ---- conv2+MLP, 64 rows/block, all weights LDS-staged ----
__global__ __launch_bounds__(256) void k_conv2f(
    const u16* __restrict__ aggH, const u16* __restrict__ h1,
    const u16* __restrict__ Wc, const int* __restrict__ flags,
    void* __restrict__ out) {
    __shared__ __align__(16) u16 wbuf[128 * TPITCH];  // 34.8 KB
    __shared__ __align__(16) u16 tile[64 * TPITCH];   // 17.4 KB -> 3 blocks/CU
    int wid = threadIdx.x >> 6, lane = threadIdx.x & 63;
    int r15 = lane & 15, quad = lane >> 4;
    int rb = blockIdx.x * 64;
    int ar = rb + wid * 16 + r15; if (ar > N_NODES - 1) ar = N_NODES - 1;
    int arl = wid * 16 + r15;

    bf16x8 at[4], as[4];
#pragma unroll
    for (int ks = 0; ks < 4; ks++) {
        int ko = ks * 32 + quad * 8;
        at[ks] = ldfrag(aggH, ar, ko);
        as[ks] = ldfrag(h1, ar, ko);
    }
    f32x4 acc2[8] = {};
    stage_w(Wc + W_W2L, wbuf);
    __syncthreads();
#pragma unroll
    for (int ks = 0; ks < 4; ks++) {
        int ko = ks * 32 + quad * 8;
#pragma unroll
        for (int ct = 0; ct < 8; ct++)
            acc2[ct] = mfma16(at[ks], ldfrag_lds(wbuf, ct * 16 + r15, ko), acc2[ct]);
    }
    __syncthreads();
    stage_w(Wc + W_W2R, wbuf);
    __syncthreads();
#pragma unroll
    for (int ks = 0; ks < 4; ks++) {
        int ko = ks * 32 + quad * 8;
#pragma unroll
        for (int ct = 0; ct < 8; ct++)
            acc2[ct] = mfma16(as[ks], ldfrag_lds(wbuf, ct * 16 + r15, ko), acc2[ct]);
    }
#pragma unroll
    for (int ct = 0; ct < 8; ct++) {  // h2 -> tile (wave-local rows; wbuf untouched)
        int col = ct * 16 + r15;
        float bb = b2f(Wc[W_B2 + col]);
#pragma unroll
        for (int r = 0; r < 4; r++) {
            int lr = wid * 16 + quad * 4 + r;
            tile[lr * TPITCH + col] = f2b(acc2[ct][r] + bb);
        }
    }
    __syncthreads();  // W2r reads done + h2 visible

    float pr[4] = {};
    float b4f = b2f(Wc[W_B4]);
#pragma unroll
    for (int half = 0; half < 2; half++) {
        stage_w(Wc + W_W3 + half * 16384, wbuf);
        __syncthreads();
        f32x4 acc3[8] = {};
#pragma unroll
        for (int ks = 0; ks < 4; ks++) {
            int ko = ks * 32 + quad * 8;
            bf16x8 a = ldfrag_lds(tile, arl, ko);
#pragma unroll
            for (int ct = 0; ct < 8; ct++)
                acc3[ct] = mfma16(a, ldfrag_lds(wbuf, ct * 16 + r15, ko), acc3[ct]);
        }
#pragma unroll
        for (int ct = 0; ct < 8; ct++) {
            int col = half * 128 + ct * 16 + r15;
            float bb = b2f(Wc[W_B3 + col]);
            float w4 = b2f(Wc[W_W4 + col]);
#pragma unroll
            for (int r = 0; r < 4; r++)
                pr[r] += fmaxf(acc3[ct][r] + bb, 0.f) * w4;
        }
        __syncthreads();  // done reading this W3 half before restage
    }
#pragma unroll
    for (int m = 1; m < 16; m <<= 1)
#pragma unroll
        for (int r = 0; r < 4; r++)
            pr[r] += __shfl_xor(pr[r], m, 64);
    if (r15 == 0) {
        int isf = flags[1];
#pragma unroll
        for (int r = 0; r < 4; r++) {
            int row = rb + wid * 16 + quad * 4 + r;
            if (row < N_NODES) {
                float v = pr[r] + b4f;
                if (isf) ((float*)out)[row] = v;
                else     ((u16*)out)[row] = f2b(v);
            }
        }
    }
}

// ============ SMALL-tier kernels (proven R5 path) ============
__global__ __launch_bounds__(256) void k_hist(const int* __restrict__ ei,
                                              int* __restrict__ cnt,
                                              const int* __restrict__ flags) {
    int e = blockIdx.x * 256 + threadIdx.x;
    if (e >= N_EDGES) return;
    int src, dst; load_edge(ei, flags[0], e, src, dst);
    if ((u32)src < N_NODES && (u32)dst < N_NODES) atomicAdd(&cnt[dst], 1);
}
__global__ __launch_bounds__(1024) void k_scan(int* __restrict__ cnt,
                                               int* __restrict__ off) {
    __shared__ int buf[1024];
    __shared__ int carry_s;
    int t = threadIdx.x;
    if (t == 0) carry_s = 0;
    __syncthreads();
    for (int base = 0; base < N_NODES; base += 1024) {
        int i = base + t;
        int v = (i < N_NODES) ? cnt[i] : 0;
        buf[t] = v;
        __syncthreads();
        for (int s = 1; s < 1024; s <<= 1) {
            int a = (t >= s) ? buf[t - s] : 0;
            __syncthreads();
            buf[t] += a;
            __syncthreads();
        }
        int carry = carry_s;
        if (i < N_NODES) {
            int excl = carry + buf[t] - v;
            off[i] = excl;
            cnt[i] = excl;
        }
        __syncthreads();
        if (t == 1023) carry_s = carry + buf[1023];
        __syncthreads();
    }
    if (t == 0) off[N_NODES] = carry_s;
}
__global__ __launch_bounds__(256) void k_csr(const int* __restrict__ ei,
                                             int* __restrict__ cursor,
                                             int* __restrict__ csr,
                                             const int* __restrict__ flags) {
    int e = blockIdx.x * 256 + threadIdx.x;
    if (e >= N_EDGES) return;
    int src, dst; load_edge(ei, flags[0], e, src, dst);
    if ((u32)src < N_NODES && (u32)dst < N_NODES) {
        int pos = atomicAdd(&cursor[dst], 1);
        if ((u32)pos < N_EDGES) csr[pos] = src;
    }
}
__device__ inline void agg_bf16(const u16* __restrict__ feat,
                                const int* __restrict__ off, const int* __restrict__ csr,
                                u16* tile, int rb, int wid, int lane) {
    const u32* f32p = (const u32*)feat;
    for (int rr = 0; rr < 32; rr++) {
        int lr = wid * 32 + rr;
        int node = rb + lr;
        float s0 = 0.f, s1 = 0.f;
        int deg = 0;
        if (node < N_NODES) {
            int s = off[node], e = off[node + 1];
            if (s < 0) s = 0;
            if (e > N_EDGES) e = N_EDGES;
            if (e < s) e = s;
            deg = e - s;
            for (int p = s; p < e; p++) {
                int nb = csr[p];
                if ((u32)nb >= N_NODES) nb = 0;
                u32 u = f32p[(size_t)nb * 64 + lane];
                s0 += b2f_lo(u); s1 += b2f_hi(u);
            }
        }
        float sc = deg > 0 ? 1.f / (float)deg : 0.f;
        u16 h0 = f2b(s0 * sc), h1 = f2b(s1 * sc);
        ((u32*)tile)[lr * (TPITCH / 2) + lane] = (u32)h0 | ((u32)h1 << 16);
    }
}
__device__ inline void agg_f32(const float* __restrict__ feat,
                               const int* __restrict__ off, const int* __restrict__ csr,
                               u16* tile, int rb, int wid, int lane) {
    const float2* fp = (const float2*)feat;
    for (int rr = 0; rr < 32; rr++) {
        int lr = wid * 32 + rr;
        int node = rb + lr;
        float s0 = 0.f, s1 = 0.f;
        int deg = 0;
        if (node < N_NODES) {
            int s = off[node], e = off[node + 1];
            if (s < 0) s = 0;
            if (e > N_EDGES) e = N_EDGES;
            if (e < s) e = s;
            deg = e - s;
            for (int p = s; p < e; p++) {
                int nb = csr[p];
                if ((u32)nb >= N_NODES) nb = 0;
                float2 v = fp[(size_t)nb * 64 + lane];
                s0 += v.x; s1 += v.y;
            }
        }
        float sc = deg > 0 ? 1.f / (float)deg : 0.f;
        u16 h0 = f2b(s0 * sc), h1 = f2b(s1 * sc);
        ((u32*)tile)[lr * (TPITCH / 2) + lane] = (u32)h0 | ((u32)h1 << 16);
    }
}
__global__ __launch_bounds__(256) void k_conv1(
    const void* __restrict__ x, const int* __restrict__ off, const int* __restrict__ csr,
    const u16* __restrict__ Wc, const int* __restrict__ flags,
    u16* __restrict__ h1) {
    __shared__ __align__(16) u16 tile[128 * TPITCH];
    int wid = threadIdx.x >> 6, lane = threadIdx.x & 63;
    int r15 = lane & 15, quad = lane >> 4;
    int rb = blockIdx.x * 128;
    int isf = flags[1];
    if (isf) agg_f32((const float*)x, off, csr, tile, rb, wid, lane);
    else     agg_bf16((const u16*)x, off, csr, tile, rb, wid, lane);
    __syncthreads();
    int ar0l = wid * 32 + r15, ar1l = ar0l + 16;
    int ar0g = rb + ar0l; if (ar0g > N_NODES - 1) ar0g = N_NODES - 1;
    int ar1g = rb + ar1l; if (ar1g > N_NODES - 1) ar1g = N_NODES - 1;
    bf16x8 ax0[4], ax1[4];
    if (isf) {
#pragma unroll
        for (int ks = 0; ks < 4; ks++) {
            int ko = ks * 32 + quad * 8;
            ax0[ks] = ldfrag_f32((const float*)x, ar0g, ko);
            ax1[ks] = ldfrag_f32((const float*)x, ar1g, ko);
        }
    } else {
#pragma unroll
        for (int ks = 0; ks < 4; ks++) {
            int ko = ks * 32 + quad * 8;
            ax0[ks] = ldfrag((const u16*)x, ar0g, ko);
            ax1[ks] = ldfrag((const u16*)x, ar1g, ko);
        }
    }
    f32x4 acc[2][8] = {};
#pragma unroll
    for (int ks = 0; ks < 4; ks++) {
        int ko = ks * 32 + quad * 8;
        bf16x8 a0t = ldfrag_lds(tile, ar0l, ko);
        bf16x8 a1t = ldfrag_lds(tile, ar1l, ko);
#pragma unroll
        for (int ct = 0; ct < 8; ct++) {
            bf16x8 bl = ldfrag(Wc + W_W1L, ct * 16 + r15, ko);
            bf16x8 br = ldfrag(Wc + W_W1R, ct * 16 + r15, ko);
            acc[0][ct] = mfma16(a0t, bl, acc[0][ct]);
            acc[0][ct] = mfma16(ax0[ks], br, acc[0][ct]);
            acc[1][ct] = mfma16(a1t, bl, acc[1][ct]);
            acc[1][ct] = mfma16(ax1[ks], br, acc[1][ct]);
        }
    }
#pragma unroll
    for (int ct = 0; ct < 8; ct++) {
        int col = ct * 16 + r15;
        float bb = b2f(Wc[W_B1 + col]);
#pragma unroll
        for (int rt = 0; rt < 2; rt++) {
#pragma unroll
            for (int r = 0; r < 4; r++) {
                int row = rb + wid * 32 + rt * 16 + quad * 4 + r;
                if (row < N_NODES)
                    h1[(size_t)row * 128 + col] = f2b(fmaxf(acc[rt][ct][r] + bb, 0.f));
            }
        }
    }
}
__global__ __launch_bounds__(256) void k_conv2mlp(
    const u16* __restrict__ h1, const int* __restrict__ off, const int* __restrict__ csr,
    const u16* __restrict__ Wc, const int* __restrict__ flags,
    void* __restrict__ out) {
    __shared__ __align__(16) u16 tile[128 * TPITCH];
    int wid = threadIdx.x >> 6, lane = threadIdx.x & 63;
    int r15 = lane & 15, quad = lane >> 4;
    int rb = blockIdx.x * 128;
    agg_bf16(h1, off, csr, tile, rb, wid, lane);
    __syncthreads();
    int ar0l = wid * 32 + r15, ar1l = ar0l + 16;
    int ar0g = rb + ar0l; if (ar0g > N_NODES - 1) ar0g = N_NODES - 1;
    int ar1g = rb + ar1l; if (ar1g > N_NODES - 1) ar1g = N_NODES - 1;
    f32x4 acc2[2][8] = {};
#pragma unroll
    for (int ks = 0; ks < 4; ks++) {
        int ko = ks * 32 + quad * 8;
        bf16x8 a0t = ldfrag_lds(tile, ar0l, ko);
        bf16x8 a1t = ldfrag_lds(tile, ar1l, ko);
        bf16x8 a0s = ldfrag(h1, ar0g, ko);
        bf16x8 a1s = ldfrag(h1, ar1g, ko);
#pragma unroll
        for (int ct = 0; ct < 8; ct++) {
            bf16x8 bl = ldfrag(Wc + W_W2L, ct * 16 + r15, ko);
            bf16x8 br = ldfrag(Wc + W_W2R, ct * 16 + r15, ko);
            acc2[0][ct] = mfma16(a0t, bl, acc2[0][ct]);
            acc2[0][ct] = mfma16(a0s, br, acc2[0][ct]);
            acc2[1][ct] = mfma16(a1t, bl, acc2[1][ct]);
            acc2[1][ct] = mfma16(a1s, br, acc2[1][ct]);
        }
    }
    __syncthreads();
#pragma unroll
    for (int ct = 0; ct < 8; ct++) {
        int col = ct * 16 + r15;
        float bb = b2f(Wc[W_B2 + col]);
#pragma unroll
        for (int rt = 0; rt < 2; rt++) {
#pragma unroll
            for (int r = 0; r < 4; r++) {
                int lr = wid * 32 + rt * 16 + quad * 4 + r;
                tile[lr * TPITCH + col] = f2b(acc2[rt][ct][r] + bb);
            }
        }
    }
    __syncthreads();
    float pr[2][4] = {};
    float b4f = b2f(Wc[W_B4]);
#pragma unroll
    for (int half = 0; half < 2; half++) {
        f32x4 acc3[2][8] = {};
#pragma unroll
        for (int ks = 0; ks < 4; ks++) {
            int ko = ks * 32 + quad * 8;
            bf16x8 a0 = ldfrag_lds(tile, ar0l, ko);
            bf16x8 a1 = ldfrag_lds(tile, ar1l, ko);
#pragma unroll
            for (int ct = 0; ct < 8; ct++) {
                bf16x8 b = ldfrag(Wc + W_W3, half * 128 + ct * 16 + r15, ko);
                acc3[0][ct] = mfma16(a0, b, acc3[0][ct]);
                acc3[1][ct] = mfma16(a1, b, acc3[1][ct]);
            }
        }
#pragma unroll
        for (int ct = 0; ct < 8; ct++) {
            int col = half * 128 + ct * 16 + r15;
            float bb = b2f(Wc[W_B3 + col]);
            float w4 = b2f(Wc[W_W4 + col]);
#pragma unroll
            for (int rt = 0; rt < 2; rt++)
#pragma unroll
                for (int r = 0; r < 4; r++)
                    pr[rt][r] += fmaxf(acc3[rt][ct][r] + bb, 0.f) * w4;
        }
    }
#pragma unroll
    for (int m = 1; m < 16; m <<= 1)
#pragma unroll
        for (int rt = 0; rt < 2; rt++)
#pragma unroll
            for (int r = 0; r < 4; r++)
                pr[rt][r] += __shfl_xor(pr[rt][r], m, 64);
    if (r15 == 0) {
        int isf = flags[1];
#pragma unroll
        for (int rt = 0; rt < 2; rt++) {
#pragma unroll
            for (int r = 0; r < 4; r++) {
                int row = rb + wid * 32 + rt * 16 + quad * 4 + r;
                if (row < N_NODES) {
                    float v = pr[rt][r] + b4f;
                    if (isf) ((float*)out)[row] = v;
                    else     ((u16*)out)[row] = f2b(v);
                }
            }
        }
    }
}

extern "C" void kernel_launch(void* const* d_in, const int* in_sizes, int n_in,
                              void* d_out, int out_size, void* d_ws, size_t ws_size,
                              hipStream_t stream) {
    const void* x  = d_in[0];
    const int* ei  = (const int*)d_in[1];

    const size_t A = 256;
    const size_t sFlg  = 256;
    const size_t sGcur = 1024;
    const size_t sGh   = (((size_t)NBIN * NPART * 4) + A - 1) & ~(A - 1);
    const size_t sCnt  = (((size_t)N_NODES * 4) + A - 1) & ~(A - 1);
    const size_t sOffN = (((size_t)N_NODES * 4) + A - 1) & ~(A - 1);
    const size_t sWc   = ((WTOT * 2) + A - 1) & ~(A - 1);
    const size_t sCsrB = (((size_t)NBIN * BCAP * 4) + A - 1) & ~(A - 1);
    const size_t sFB   = (((size_t)N_NODES * 128 * 2) + A - 1) & ~(A - 1);
    const size_t sOff  = (((size_t)(N_NODES + 1) * 4) + A - 1) & ~(A - 1);
    const size_t sCsr  = (((size_t)N_EDGES * 4) + A - 1) & ~(A - 1);
    const size_t needB1 = sFlg + sGcur + 2 * sGh + sCnt + sOffN + sWc + sCsrB + 2 * sFB;
    const size_t needB0 = needB1 + sFB;
    const size_t needS  = sFlg + sCnt + sOff + sCsr + sFB;

    char* ws = (char*)d_ws;
    int gconv = (N_NODES + 63) / 64;
    int gagg  = (N_NODES + 3) / 4;

    CvtArgs ca;
    const int srcIdx[10] = {2, 4, 5, 7, 8, 10, 3, 6, 9, 11};
    const int offs[10] = {W_W1L, W_W1R, W_W2L, W_W2R, W_W3, W_W4, W_B1, W_B2, W_B3, W_B4};
    const int ns[10]   = {16384, 16384, 16384, 16384, 32768, 256, 128, 128, 256, 1};
    for (int i = 0; i < 10; i++) { ca.src[i] = d_in[srcIdx[i]]; ca.off[i] = offs[i]; ca.n[i] = ns[i]; }

    if (ws_size >= needB1) {
        bool t0 = ws_size >= needB0;
        int* flags = (int*)ws;
        int* gcur  = (int*)(ws + sFlg);
        int* ghist = (int*)(ws + sFlg + sGcur);
        int* gbase = (int*)(ws + sFlg + sGcur + sGh);
        int* cnt   = (int*)(ws + sFlg + sGcur + 2 * sGh);
        int* offN  = (int*)(ws + sFlg + sGcur + 2 * sGh + sCnt);
        u16* Wc    = (u16*)(ws + sFlg + sGcur + 2 * sGh + sCnt + sOffN);
        u32* csrb  = (u32*)(ws + sFlg + sGcur + 2 * sGh + sCnt + sOffN + sWc);
        u16* B1    = (u16*)(ws + sFlg + sGcur + 2 * sGh + sCnt + sOffN + sWc + sCsrB);
        u16* B2    = B1 + (sFB / 2);
        u32* gbuf  = (u32*)B2;         // dead after k_binB
        u16* xb    = B2 + (sFB / 2);   // T0 only

        hipMemsetAsync(ws, 0, sFlg, stream);
        k_detects<<<2, 256, 0, stream>>>((const u64*)ei, (const u32*)x, flags);
        k_rhist<<<NPART, 256, 0, stream>>>(ei, ghist, flags);
        k_rscan<<<NBIN, 512, 0, stream>>>(ghist, gbase, gcur);
        k_rscatter<<<NPART, 256, 0, stream>>>(ei, gbase, gbuf, flags);
        k_binB<<<NBIN, 512, 0, stream>>>(gcur, gbuf, csrb, cnt, offN);
        k_cvtw<<<(WTOT + 255) / 256, 256, 0, stream>>>(ca, Wc, flags);

        if (t0) {
            k_cvtx<<<((N_NODES * 128 / 4) + 255) / 256, 256, 0, stream>>>(x, xb, flags);
            k_aggc<<<gagg, 256, 0, stream>>>(xb, cnt, offN, csrb, B1);
            k_conv1f<false><<<gconv, 256, 0, stream>>>(B1, xb, Wc, flags, B2);
        } else {
            k_aggcx<<<gagg, 256, 0, stream>>>(x, cnt, offN, csrb, flags, B1);
            k_conv1f<true><<<gconv, 256, 0, stream>>>(B1, x, Wc, flags, B2);
        }
        k_aggc<<<gagg, 256, 0, stream>>>(B2, cnt, offN, csrb, B1);
        k_conv2f<<<gconv, 256, 0, stream>>>(B1, B2, Wc, flags, d_out);
    } else if (ws_size >= needS) {
        int* flags = (int*)ws;
        int* cnt   = (int*)(ws + sFlg);
        u16* Wc    = (u16*)(ws + sFlg);
        int* off   = (int*)(ws + sFlg + sCnt);
        int* csr   = (int*)(ws + sFlg + sCnt + sOff);
        u16* h1    = (u16*)(ws + sFlg + sCnt + sOff + sCsr);

        hipMemsetAsync(ws, 0, sFlg + (size_t)N_NODES * 4, stream);
        k_detects<<<2, 256, 0, stream>>>((const u64*)ei, (const u32*)x, flags);
        k_hist<<<N_EDGES / 256, 256, 0, stream>>>(ei, cnt, flags);
        k_scan<<<1, 1024, 0, stream>>>(cnt, off);
        k_csr<<<N_EDGES / 256, 256, 0, stream>>>(ei, cnt, csr, flags);
        k_cvtw<<<(WTOT + 255) / 256, 256, 0, stream>>>(ca, Wc, flags);
        k_conv1<<<(N_NODES + 127) / 128, 256, 0, stream>>>(x, off, csr, Wc, flags, h1);
        k_conv2mlp<<<(N_NODES + 127) / 128, 256, 0, stream>>>(h1, off, csr, Wc, flags, d_out);
    } else {
        k_diag<<<(N_NODES + 255) / 256, 256, 0, stream>>>(
            (u16*)d_out, 2000.0f + (float)(ws_size >> 20));
    }
}

// Round 6
// 327.267 us; speedup vs baseline: 1.5349x; 1.0634x over previous
//
#include <hip/hip_runtime.h>

typedef unsigned short u16;
typedef unsigned int u32;
typedef unsigned long long u64;

#define N_NODES 100000
#define N_EDGES 1600000
#define TPITCH 136   // LDS pitch (u16): 272B rows, 16B-aligned
#define NBIN 196     // ceil(N_NODES/512)
#define BCAP 12288   // per-bin pair capacity
#define NPART 512    // radix partition blocks
#define EPB 3125     // edges per partition
#define CVX_BLOCKS 12500  // N_NODES*128/4/256 exactly

typedef __bf16 bf16x8 __attribute__((ext_vector_type(8)));
typedef float  f32x4  __attribute__((ext_vector_type(4)));

__device__ inline float b2f(u16 b) { return __uint_as_float(((u32)b) << 16); }
__device__ inline float b2f_lo(u32 u) { return __uint_as_float(u << 16); }
__device__ inline float b2f_hi(u32 u) { return __uint_as_float(u & 0xffff0000u); }
__device__ inline u16 f2b(float f) {  // RNE float->bf16
    u32 u = __float_as_uint(f);
    return (u16)((u + 0x7fffu + ((u >> 16) & 1u)) >> 16);
}

__device__ inline bf16x8 ldfrag(const u16* base, int row, int k) {
    union { uint4 u; bf16x8 v; } t;
    t.u = *(const uint4*)(base + (size_t)row * 128 + k);
    return t.v;
}
__device__ inline bf16x8 ldfrag_f32(const float* base, int row, int k) {
    const float4* p = (const float4*)(base + (size_t)row * 128 + k);
    float4 a = p[0], b = p[1];
    union { u16 h[8]; bf16x8 v; } t;
    t.h[0] = f2b(a.x); t.h[1] = f2b(a.y); t.h[2] = f2b(a.z); t.h[3] = f2b(a.w);
    t.h[4] = f2b(b.x); t.h[5] = f2b(b.y); t.h[6] = f2b(b.z); t.h[7] = f2b(b.w);
    return t.v;
}
__device__ inline bf16x8 ldfrag_lds(const u16* tile, int lrow, int k) {
    union { uint4 u; bf16x8 v; } t;
    t.u = *(const uint4*)(tile + lrow * TPITCH + k);
    return t.v;
}
__device__ inline f32x4 mfma16(bf16x8 a, bf16x8 b, f32x4 c) {
    return __builtin_amdgcn_mfma_f32_16x16x32_bf16(a, b, c, 0, 0, 0);
}

// cooperative stage: 128x128 bf16 = 2048 16B chunks; 256 thr x 8 iters
__device__ inline void stage_w(const u16* __restrict__ g, u16* lds) {
    int t = threadIdx.x;
#pragma unroll
    for (int i = 0; i < 8; i++) {
        int u = t + i * 256;
        int row = u >> 4, k = (u & 15) * 8;
        *(uint4*)(lds + row * TPITCH + k) = *(const uint4*)(g + row * 128 + k);
    }
}

// ---- diagnostic ----
__global__ __launch_bounds__(256) void k_diag(u16* __restrict__ out, float val) {
    int i = blockIdx.x * 256 + threadIdx.x;
    if (i < N_NODES) out[i] = f2b(val);
}

// ---- combined detect (R5: self-contained, plain store; no memset needed) ----
__global__ __launch_bounds__(256) void k_detects(const u64* __restrict__ e,
                                                 const u32* __restrict__ x,
                                                 int* __restrict__ flags) {
    __shared__ int bad_s;
    int t = threadIdx.x;
    if (t == 0) bad_s = 0;
    __syncthreads();
    if (blockIdx.x == 0) {
        u64 v = 0;
#pragma unroll
        for (int i = 0; i < 4; i++) v |= e[t + 256 * i];
        if (v >> 32) atomicOr(&bad_s, 1);
    } else {
        int bad = 0;
#pragma unroll
        for (int i = 0; i < 4; i++) {
            u32 w = x[t + 256 * i];
            u32 ex = (w >> 7) & 0xff;
            if (ex < 100 || ex > 140) bad = 1;
        }
        if (bad) atomicOr(&bad_s, 1);
    }
    __syncthreads();
    if (t == 0) flags[blockIdx.x] = bad_s;
}

__device__ inline void load_edge(const int* ei, int is32, int e, int& src, int& dst) {
    if (is32) {
        src = ei[e]; dst = ei[N_EDGES + e];
    } else {
        const long long* e64 = (const long long*)ei;
        src = (int)e64[e]; dst = (int)e64[N_EDGES + e];
    }
}

// ---- radix partition build (proven R9/R11) ----
__global__ __launch_bounds__(256) void k_rhist(const int* __restrict__ ei,
                                               int* __restrict__ ghist,
                                               const int* __restrict__ flags) {
    __shared__ int hist[NBIN];
    int p = blockIdx.x, t = threadIdx.x;
    for (int i = t; i < NBIN; i += 256) hist[i] = 0;
    __syncthreads();
    int is32 = flags[0];
    int base = p * EPB;
    int end = base + EPB; if (end > N_EDGES) end = N_EDGES;
    for (int e = base + t; e < end; e += 256) {
        int src, dst; load_edge(ei, is32, e, src, dst);
        if ((u32)src < N_NODES && (u32)dst < N_NODES) atomicAdd(&hist[dst >> 9], 1);
    }
    __syncthreads();
    for (int i = t; i < NBIN; i += 256) ghist[i * NPART + p] = hist[i];
}
__global__ __launch_bounds__(512) void k_rscan(const int* __restrict__ ghist,
                                               int* __restrict__ gbase,
                                               int* __restrict__ gcur) {
    __shared__ int buf[NPART];
    int b = blockIdx.x, t = threadIdx.x;
    int v = ghist[b * NPART + t];
    buf[t] = v;
    __syncthreads();
    for (int s = 1; s < NPART; s <<= 1) {
        int a = (t >= s) ? buf[t - s] : 0;
        __syncthreads();
        buf[t] += a;
        __syncthreads();
    }
    gbase[b * NPART + t] = buf[t] - v;
    if (t == NPART - 1) gcur[b] = buf[t];
}
__global__ __launch_bounds__(256) void k_rscatter(const int* __restrict__ ei,
                                                  const int* __restrict__ gbase,
                                                  u32* __restrict__ gbuf,
                                                  const int* __restrict__ flags) {
    __shared__ int cur[NBIN];
    int p = blockIdx.x, t = threadIdx.x;
    for (int i = t; i < NBIN; i += 256) cur[i] = gbase[i * NPART + p];
    __syncthreads();
    int is32 = flags[0];
    int base = p * EPB;
    int end = base + EPB; if (end > N_EDGES) end = N_EDGES;
    for (int e = base + t; e < end; e += 256) {
        int src, dst; load_edge(ei, is32, e, src, dst);
        if ((u32)src < N_NODES && (u32)dst < N_NODES) {
            int bin = dst >> 9;
            int pos = atomicAdd(&cur[bin], 1);
            if (pos < BCAP)
                gbuf[(size_t)bin * BCAP + pos] = ((u32)(dst & 511) << 17) | (u32)src;
        }
    }
}
__global__ __launch_bounds__(512) void k_binB(const int* __restrict__ gcur,
                                              const u32* __restrict__ gbuf,
                                              u32* __restrict__ csr,
                                              int* __restrict__ cnt,
                                              int* __restrict__ offN) {
    __shared__ int hist[512];
    __shared__ int pfx[512];
    __shared__ int cur[512];
    __shared__ u32 srcbuf[BCAP];
    int b = blockIdx.x, t = threadIdx.x;
    int n = gcur[b]; if (n > BCAP) n = BCAP;
    hist[t] = 0;
    __syncthreads();
    for (int i = t; i < n; i += 512)
        atomicAdd(&hist[gbuf[(size_t)b * BCAP + i] >> 17], 1);
    __syncthreads();
    pfx[t] = hist[t];
    __syncthreads();
    for (int s = 1; s < 512; s <<= 1) {
        int a = (t >= s) ? pfx[t - s] : 0;
        __syncthreads();
        pfx[t] += a;
        __syncthreads();
    }
    int excl = pfx[t] - hist[t];
    cur[t] = excl;
    __syncthreads();
    for (int i = t; i < n; i += 512) {
        u32 p = gbuf[(size_t)b * BCAP + i];
        int pos = atomicAdd(&cur[p >> 17], 1);
        if (pos < BCAP) srcbuf[pos] = p & 0x1FFFFu;
    }
    __syncthreads();
    int total = pfx[511];
    for (int i = t; i < total; i += 512)
        csr[(size_t)b * BCAP + i] = srcbuf[i];
    int node = b * 512 + t;
    if (node < N_NODES) {
        cnt[node] = hist[t];
        offN[node] = b * BCAP + excl;
    }
}

// ---- weight normalization -> bf16 ----
#define WTOT 99073
struct CvtArgs { const void* src[10]; int off[10]; int n[10]; };
__device__ inline void cvtw_body(const CvtArgs& a, u16* __restrict__ dst,
                                 int i, int isf) {
    int s = 0;
    while (s < 9 && i >= a.off[s + 1]) s++;
    int j = i - a.off[s];
    float v = isf ? ((const float*)a.src[s])[j] : b2f(((const u16*)a.src[s])[j]);
    dst[i] = f2b(v);
}
__global__ __launch_bounds__(256) void k_cvtw(CvtArgs a, u16* __restrict__ dst,
                                              const int* __restrict__ flags) {
    int i = blockIdx.x * 256 + threadIdx.x;
    if (i >= WTOT) return;
    cvtw_body(a, dst, i, flags[1]);
}
#define W_W1L 0
#define W_W1R 16384
#define W_W2L 32768
#define W_W2R 49152
#define W_W3  65536
#define W_W4  98304
#define W_B1  98560
#define W_B2  98688
#define W_B3  98816
#define W_B4  99072

// ---- R5 merged: x -> bf16 convert + weight convert in one launch (T0) ----
__global__ __launch_bounds__(256) void k_cvtxw(const void* __restrict__ x,
                                               u16* __restrict__ xb,
                                               CvtArgs a, u16* __restrict__ Wc,
                                               const int* __restrict__ flags) {
    int b = blockIdx.x;
    int isf = flags[1];
    if (b < CVX_BLOCKS) {
        int i = b * 256 + threadIdx.x;   // < 3.2M exactly
        if (isf) {
            float4 v = ((const float4*)x)[i];
            union { u16 h[4]; u64 q; } t;
            t.h[0] = f2b(v.x); t.h[1] = f2b(v.y); t.h[2] = f2b(v.z); t.h[3] = f2b(v.w);
            ((u64*)xb)[i] = t.q;
        } else {
            ((u64*)xb)[i] = ((const u64*)x)[i];
        }
    } else {
        int i = (b - CVX_BLOCKS) * 256 + threadIdx.x;
        if (i >= WTOT) return;
        cvtw_body(a, Wc, i, isf);
    }
}

// ---- compact-CSR agg, bf16 features: one wave/node, 8-deep ILP (R0 proven) ----
__global__ __launch_bounds__(256) void k_aggc(const u16* __restrict__ feat,
                                              const int* __restrict__ cnt,
                                              const int* __restrict__ offN,
                                              const u32* __restrict__ csr,
                                              u16* __restrict__ outb) {
    int node = blockIdx.x * 4 + (threadIdx.x >> 6);
    if (node >= N_NODES) return;
    int lane = threadIdx.x & 63;
    int deg = cnt[node];
    int s = offN[node];
    const u32* f = (const u32*)feat;
    float a0 = 0, a1 = 0, b0 = 0, b1 = 0, c0 = 0, c1 = 0, d0 = 0, d1 = 0;
    float e0 = 0, e1 = 0, g0 = 0, g1 = 0, h0f = 0, h1f = 0, i0 = 0, i1 = 0;
    int p = 0;
    for (; p + 7 < deg; p += 8) {
        u32 n0 = csr[s + p],     n1 = csr[s + p + 1], n2 = csr[s + p + 2], n3 = csr[s + p + 3];
        u32 n4 = csr[s + p + 4], n5 = csr[s + p + 5], n6 = csr[s + p + 6], n7 = csr[s + p + 7];
        if (n0 >= N_NODES) n0 = 0;
        if (n1 >= N_NODES) n1 = 0;
        if (n2 >= N_NODES) n2 = 0;
        if (n3 >= N_NODES) n3 = 0;
        if (n4 >= N_NODES) n4 = 0;
        if (n5 >= N_NODES) n5 = 0;
        if (n6 >= N_NODES) n6 = 0;
        if (n7 >= N_NODES) n7 = 0;
        u32 w0 = f[(size_t)n0 * 64 + lane];
        u32 w1 = f[(size_t)n1 * 64 + lane];
        u32 w2 = f[(size_t)n2 * 64 + lane];
        u32 w3 = f[(size_t)n3 * 64 + lane];
        u32 w4 = f[(size_t)n4 * 64 + lane];
        u32 w5 = f[(size_t)n5 * 64 + lane];
        u32 w6 = f[(size_t)n6 * 64 + lane];
        u32 w7 = f[(size_t)n7 * 64 + lane];
        a0 += b2f_lo(w0); a1 += b2f_hi(w0);
        b0 += b2f_lo(w1); b1 += b2f_hi(w1);
        c0 += b2f_lo(w2); c1 += b2f_hi(w2);
        d0 += b2f_lo(w3); d1 += b2f_hi(w3);
        e0 += b2f_lo(w4); e1 += b2f_hi(w4);
        g0 += b2f_lo(w5); g1 += b2f_hi(w5);
        h0f += b2f_lo(w6); h1f += b2f_hi(w6);
        i0 += b2f_lo(w7); i1 += b2f_hi(w7);
    }
    for (; p + 3 < deg; p += 4) {
        u32 n0 = csr[s + p], n1 = csr[s + p + 1], n2 = csr[s + p + 2], n3 = csr[s + p + 3];
        if (n0 >= N_NODES) n0 = 0;
        if (n1 >= N_NODES) n1 = 0;
        if (n2 >= N_NODES) n2 = 0;
        if (n3 >= N_NODES) n3 = 0;
        u32 w0 = f[(size_t)n0 * 64 + lane];
        u32 w1 = f[(size_t)n1 * 64 + lane];
        u32 w2 = f[(size_t)n2 * 64 + lane];
        u32 w3 = f[(size_t)n3 * 64 + lane];
        a0 += b2f_lo(w0); a1 += b2f_hi(w0);
        b0 += b2f_lo(w1); b1 += b2f_hi(w1);
        c0 += b2f_lo(w2); c1 += b2f_hi(w2);
        d0 += b2f_lo(w3); d1 += b2f_hi(w3);
    }
    for (; p < deg; p++) {
        u32 n0 = csr[s + p];
        if (n0 >= N_NODES) n0 = 0;
        u32 w0 = f[(size_t)n0 * 64 + lane];
        a0 += b2f_lo(w0); a1 += b2f_hi(w0);
    }
    float s0 = ((a0 + b0) + (c0 + d0)) + ((e0 + g0) + (h0f + i0));
    float s1 = ((a1 + b1) + (c1 + d1)) + ((e1 + g1) + (h1f + i1));
    float sc = deg > 0 ? 1.f / (float)deg : 0.f;
    u16 o0 = f2b(s0 * sc), o1 = f2b(s1 * sc);
    ((u32*)outb)[(size_t)node * 64 + lane] = (u32)o0 | ((u32)o1 << 16);
}

// ---- compact-CSR agg, dual-dtype raw x (T1) ----
__global__ __launch_bounds__(256) void k_aggcx(const void* __restrict__ x,
                                               const int* __restrict__ cnt,
                                               const int* __restrict__ offN,
                                               const u32* __restrict__ csr,
                                               const int* __restrict__ flags,
                                               u16* __restrict__ outb) {
    int node = blockIdx.x * 4 + (threadIdx.x >> 6);
    if (node >= N_NODES) return;
    int lane = threadIdx.x & 63;
    int deg = cnt[node];
    int s = offN[node];
    float a0 = 0, a1 = 0, b0 = 0, b1 = 0;
    int p = 0;
    if (flags[1]) {
        const float2* f = (const float2*)x;
        for (; p + 1 < deg; p += 2) {
            u32 n0 = csr[s + p], n1 = csr[s + p + 1];
            if (n0 >= N_NODES) n0 = 0;
            if (n1 >= N_NODES) n1 = 0;
            float2 w0 = f[(size_t)n0 * 64 + lane];
            float2 w1 = f[(size_t)n1 * 64 + lane];
            a0 += w0.x; a1 += w0.y; b0 += w1.x; b1 += w1.y;
        }
        for (; p < deg; p++) {
            u32 n0 = csr[s + p];
            if (n0 >= N_NODES) n0 = 0;
            float2 w0 = f[(size_t)n0 * 64 + lane];
            a0 += w0.x; a1 += w0.y;
        }
    } else {
        const u32* f = (const u32*)x;
        for (; p + 1 < deg; p += 2) {
            u32 n0 = csr[s + p], n1 = csr[s + p + 1];
            if (n0 >= N_NODES) n0 = 0;
            if (n1 >= N_NODES) n1 = 0;
            u32 w0 = f[(size_t)n0 * 64 + lane];
            u32 w1 = f[(size_t)n1 * 64 + lane];
            a0 += b2f_lo(w0); a1 += b2f_hi(w0);
            b0 += b2f_lo(w1); b1 += b2f_hi(w1);
        }
        for (; p < deg; p++) {
            u32 n0 = csr[s + p];
            if (n0 >= N_NODES) n0 = 0;
            u32 w0 = f[(size_t)n0 * 64 + lane];
            a0 += b2f_lo(w0); a1 += b2f_hi(w0);
        }
    }
    float s0 = a0 + b0, s1 = a1 + b1;
    float sc = deg > 0 ? 1.f / (float)deg : 0.f;
    u16 o0 = f2b(s0 * sc), o1 = f2b(s1 * sc);
    ((u32*)outb)[(size_t)node * 64 + lane] = (u32)o0 | ((u32)o1 << 16);
}

// ---- conv1, 64 rows/block, W1l/W1r LDS-staged sequentially ----
template <bool DUALX>
__global__ __launch_bounds__(256) void k_conv1f(
    const u16* __restrict__ aggA, const void* __restrict__ xself,
    const u16* __restrict__ Wc, const int* __restrict__ flags,
    u16* __restrict__ h1) {
    __shared__ __align__(16) u16 wbuf[128 * TPITCH];  // 34.8 KB -> 4 blocks/CU
    int wid = threadIdx.x >> 6, lane = threadIdx.x & 63;
    int r15 = lane & 15, quad = lane >> 4;
    int rb = blockIdx.x * 64;
    int ar = rb + wid * 16 + r15; if (ar > N_NODES - 1) ar = N_NODES - 1;

    bf16x8 ag[4], ax[4];
    bool isf = DUALX && flags[1];
#pragma unroll
    for (int ks = 0; ks < 4; ks++) {
        int ko = ks * 32 + quad * 8;
        ag[ks] = ldfrag(aggA, ar, ko);
        ax[ks] = isf ? ldfrag_f32((const float*)xself, ar, ko)
                     : ldfrag((const u16*)xself, ar, ko);
    }
    f32x4 acc[8] = {};
    stage_w(Wc + W_W1L, wbuf);
    __syncthreads();
#pragma unroll
    for (int ks = 0; ks < 4; ks++) {
        int ko = ks * 32 + quad * 8;
#pragma unroll
        for (int ct = 0; ct < 8; ct++)
            acc[ct] = mfma16(ag[ks], ldfrag_lds(wbuf, ct * 16 + r15, ko), acc[ct]);
    }
    __syncthreads();
    stage_w(Wc + W_W1R, wbuf);
    __syncthreads();
#pragma unroll
    for (int ks = 0; ks < 4; ks++) {
        int ko = ks * 32 + quad * 8;
#pragma unroll
        for (int ct = 0; ct < 8; ct++)
            acc[ct] = mfma16(ax[ks], ldfrag_lds(wbuf, ct * 16 + r15, ko), acc[ct]);
    }
#pragma unroll
    for (int ct = 0; ct < 8; ct++) {
        int col = ct * 16 + r15;
        float bb = b2f(Wc[W_B1 + col]);
#pragma unroll
        for (int r = 0; r < 4; r++) {
            int row = rb + wid * 16 + quad * 4 + r;
            if (row < N_NODES)
                h1[(size_t)row * 128 + col] = f2b(fmaxf(acc[ct][r] + bb, 0.f));
        }
    }
}

// ---- conv2+MLP, 64 rows/block, all weights LDS-staged ----
__global__ __launch_bounds__(256) void k_conv2f(
    const u16* __restrict__ aggH, const u16* __restrict__ h1,
    const u16* __restrict__ Wc, const int* __restrict__ flags,
    void* __restrict__ out) {
    __shared__ __align__(16) u16 wbuf[128 * TPITCH];  // 34.8 KB
    __shared__ __align__(16) u16 tile[64 * TPITCH];   // 17.4 KB -> 3 blocks/CU
    int wid = threadIdx.x >> 6, lane = threadIdx.x & 63;
    int r15 = lane & 15, quad = lane >> 4;
    int rb = blockIdx.x * 64;
    int ar = rb + wid * 16 + r15; if (ar > N_NODES - 1) ar = N_NODES - 1;
    int arl = wid * 16 + r15;

    bf16x8 at[4], as[4];
#pragma unroll
    for (int ks = 0; ks < 4; ks++) {
        int ko = ks * 32 + quad * 8;
        at[ks] = ldfrag(aggH, ar, ko);
        as[ks] = ldfrag(h1, ar, ko);
    }
    f32x4 acc2[8] = {};
    stage_w(Wc + W_W2L, wbuf);
    __syncthreads();
#pragma unroll
    for (int ks = 0; ks < 4; ks++) {
        int ko = ks * 32 + quad * 8;
#pragma unroll
        for (int ct = 0; ct < 8; ct++)
            acc2[ct] = mfma16(at[ks], ldfrag_lds(wbuf, ct * 16 + r15, ko), acc2[ct]);
    }
    __syncthreads();
    stage_w(Wc + W_W2R, wbuf);
    __syncthreads();
#pragma unroll
    for (int ks = 0; ks < 4; ks++) {
        int ko = ks * 32 + quad * 8;
#pragma unroll
        for (int ct = 0; ct < 8; ct++)
            acc2[ct] = mfma16(as[ks], ldfrag_lds(wbuf, ct * 16 + r15, ko), acc2[ct]);
    }
#pragma unroll
    for (int ct = 0; ct < 8; ct++) {  // h2 -> tile (wave-local rows; wbuf untouched)
        int col = ct * 16 + r15;
        float bb = b2f(Wc[W_B2 + col]);
#pragma unroll
        for (int r = 0; r < 4; r++) {
            int lr = wid * 16 + quad * 4 + r;
            tile[lr * TPITCH + col] = f2b(acc2[ct][r] + bb);
        }
    }
    __syncthreads();  // W2r reads done + h2 visible

    float pr[4] = {};
    float b4f = b2f(Wc[W_B4]);
#pragma unroll
    for (int half = 0; half < 2; half++) {
        stage_w(Wc + W_W3 + half * 16384, wbuf);
        __syncthreads();
        f32x4 acc3[8] = {};
#pragma unroll
        for (int ks = 0; ks < 4; ks++) {
            int ko = ks * 32 + quad * 8;
            bf16x8 a = ldfrag_lds(tile, arl, ko);
#pragma unroll
            for (int ct = 0; ct < 8; ct++)
                acc3[ct] = mfma16(a, ldfrag_lds(wbuf, ct * 16 + r15, ko), acc3[ct]);
        }
#pragma unroll
        for (int ct = 0; ct < 8; ct++) {
            int col = half * 128 + ct * 16 + r15;
            float bb = b2f(Wc[W_B3 + col]);
            float w4 = b2f(Wc[W_W4 + col]);
#pragma unroll
            for (int r = 0; r < 4; r++)
                pr[r] += fmaxf(acc3[ct][r] + bb, 0.f) * w4;
        }
        __syncthreads();  // done reading this W3 half before restage
    }
#pragma unroll
    for (int m = 1; m < 16; m <<= 1)
#pragma unroll
        for (int r = 0; r < 4; r++)
            pr[r] += __shfl_xor(pr[r], m, 64);
    if (r15 == 0) {
        int isf = flags[1];
#pragma unroll
        for (int r = 0; r < 4; r++) {
            int row = rb + wid * 16 + quad * 4 + r;
            if (row < N_NODES) {
                float v = pr[r] + b4f;
                if (isf) ((float*)out)[row] = v;
                else     ((u16*)out)[row] = f2b(v);
            }
        }
    }
}

// ============ SMALL-tier kernels (proven R5 path) ============
__global__ __launch_bounds__(256) void k_hist(const int* __restrict__ ei,
                                              int* __restrict__ cnt,
                                              const int* __restrict__ flags) {
    int e = blockIdx.x * 256 + threadIdx.x;
    if (e >= N_EDGES) return;
    int src, dst; load_edge(ei, flags[0], e, src, dst);
    if ((u32)src < N_NODES && (u32)dst < N_NODES) atomicAdd(&cnt[dst], 1);
}
__global__ __launch_bounds__(1024) void k_scan(int* __restrict__ cnt,
                                               int* __restrict__ off) {
    __shared__ int buf[1024];
    __shared__ int carry_s;
    int t = threadIdx.x;
    if (t == 0) carry_s = 0;
    __syncthreads();
    for (int base = 0; base < N_NODES; base += 1024) {
        int i = base + t;
        int v = (i < N_NODES) ? cnt[i] : 0;
        buf[t] = v;
        __syncthreads();
        for (int s = 1; s < 1024; s <<= 1) {
            int a = (t >= s) ? buf[t - s] : 0;
            __syncthreads();
            buf[t] += a;
            __syncthreads();
        }
        int carry = carry_s;
        if (i < N_NODES) {
            int excl = carry + buf[t] - v;
            off[i] = excl;
            cnt[i] = excl;
        }
        __syncthreads();
        if (t == 1023) carry_s = carry + buf[1023];
        __syncthreads();
    }
    if (t == 0) off[N_NODES] = carry_s;
}
__global__ __launch_bounds__(256) void k_csr(const int* __restrict__ ei,
                                             int* __restrict__ cursor,
                                             int* __restrict__ csr,
                                             const int* __restrict__ flags) {
    int e = blockIdx.x * 256 + threadIdx.x;
    if (e >= N_EDGES) return;
    int src, dst; load_edge(ei, flags[0], e, src, dst);
    if ((u32)src < N_NODES && (u32)dst < N_NODES) {
        int pos = atomicAdd(&cursor[dst], 1);
        if ((u32)pos < N_EDGES) csr[pos] = src;
    }
}
__device__ inline void agg_bf16(const u16* __restrict__ feat,
                                const int* __restrict__ off, const int* __restrict__ csr,
                                u16* tile, int rb, int wid, int lane) {
    const u32* f32p = (const u32*)feat;
    for (int rr = 0; rr < 32; rr++) {
        int lr = wid * 32 + rr;
        int node = rb + lr;
        float s0 = 0.f, s1 = 0.f;
        int deg = 0;
        if (node < N_NODES) {
            int s = off[node], e = off[node + 1];
            if (s < 0) s = 0;
            if (e > N_EDGES) e = N_EDGES;
            if (e < s) e = s;
            deg = e - s;
            for (int p = s; p < e; p++) {
                int nb = csr[p];
                if ((u32)nb >= N_NODES) nb = 0;
                u32 u = f32p[(size_t)nb * 64 + lane];
                s0 += b2f_lo(u); s1 += b2f_hi(u);
            }
        }
        float sc = deg > 0 ? 1.f / (float)deg : 0.f;
        u16 h0 = f2b(s0 * sc), h1 = f2b(s1 * sc);
        ((u32*)tile)[lr * (TPITCH / 2) + lane] = (u32)h0 | ((u32)h1 << 16);
    }
}
__device__ inline void agg_f32(const float* __restrict__ feat,
                               const int* __restrict__ off, const int* __restrict__ csr,
                               u16* tile, int rb, int wid, int lane) {
    const float2* fp = (const float2*)feat;
    for (int rr = 0; rr < 32; rr++) {
        int lr = wid * 32 + rr;
        int node = rb + lr;
        float s0 = 0.f, s1 = 0.f;
        int deg = 0;
        if (node < N_NODES) {
            int s = off[node], e = off[node + 1];
            if (s < 0) s = 0;
            if (e > N_EDGES) e = N_EDGES;
            if (e < s) e = s;
            deg = e - s;
            for (int p = s; p < e; p++) {
                int nb = csr[p];
                if ((u32)nb >= N_NODES) nb = 0;
                float2 v = fp[(size_t)nb * 64 + lane];
                s0 += v.x; s1 += v.y;
            }
        }
        float sc = deg > 0 ? 1.f / (float)deg : 0.f;
        u16 h0 = f2b(s0 * sc), h1 = f2b(s1 * sc);
        ((u32*)tile)[lr * (TPITCH / 2) + lane] = (u32)h0 | ((u32)h1 << 16);
    }
}
__global__ __launch_bounds__(256) void k_conv1(
    const void* __restrict__ x, const int* __restrict__ off, const int* __restrict__ csr,
    const u16* __restrict__ Wc, const int* __restrict__ flags,
    u16* __restrict__ h1) {
    __shared__ __align__(16) u16 tile[128 * TPITCH];
    int wid = threadIdx.x >> 6, lane = threadIdx.x & 63;
    int r15 = lane & 15, quad = lane >> 4;
    int rb = blockIdx.x * 128;
    int isf = flags[1];
    if (isf) agg_f32((const float*)x, off, csr, tile, rb, wid, lane);
    else     agg_bf16((const u16*)x, off, csr, tile, rb, wid, lane);
    __syncthreads();
    int ar0l = wid * 32 + r15, ar1l = ar0l + 16;
    int ar0g = rb + ar0l; if (ar0g > N_NODES - 1) ar0g = N_NODES - 1;
    int ar1g = rb + ar1l; if (ar1g > N_NODES - 1) ar1g = N_NODES - 1;
    bf16x8 ax0[4], ax1[4];
    if (isf) {
#pragma unroll
        for (int ks = 0; ks < 4; ks++) {
            int ko = ks * 32 + quad * 8;
            ax0[ks] = ldfrag_f32((const float*)x, ar0g, ko);
            ax1[ks] = ldfrag_f32((const float*)x, ar1g, ko);
        }
    } else {
#pragma unroll
        for (int ks = 0; ks < 4; ks++) {
            int ko = ks * 32 + quad * 8;
            ax0[ks] = ldfrag((const u16*)x, ar0g, ko);
            ax1[ks] = ldfrag((const u16*)x, ar1g, ko);
        }
    }
    f32x4 acc[2][8] = {};
#pragma unroll
    for (int ks = 0; ks < 4; ks++) {
        int ko = ks * 32 + quad * 8;
        bf16x8 a0t = ldfrag_lds(tile, ar0l, ko);
        bf16x8 a1t = ldfrag_lds(tile, ar1l, ko);
#pragma unroll
        for (int ct = 0; ct < 8; ct++) {
            bf16x8 bl = ldfrag(Wc + W_W1L, ct * 16 + r15, ko);
            bf16x8 br = ldfrag(Wc + W_W1R, ct * 16 + r15, ko);
            acc[0][ct] = mfma16(a0t, bl, acc[0][ct]);
            acc[0][ct] = mfma16(ax0[ks], br, acc[0][ct]);
            acc[1][ct] = mfma16(a1t, bl, acc[1][ct]);
            acc[1][ct] = mfma16(ax1[ks], br, acc[1][ct]);
        }
    }
#pragma unroll
    for (int ct = 0; ct < 8; ct++) {
        int col = ct * 16 + r15;
        float bb = b2f(Wc[W_B1 + col]);
#pragma unroll
        for (int rt = 0; rt < 2; rt++) {
#pragma unroll
            for (int r = 0; r < 4; r++) {
                int row = rb + wid * 32 + rt * 16 + quad * 4 + r;
                if (row < N_NODES)
                    h1[(size_t)row * 128 + col] = f2b(fmaxf(acc[rt][ct][r] + bb, 0.f));
            }
        }
    }
}
__global__ __launch_bounds__(256) void k_conv2mlp(
    const u16* __restrict__ h1, const int* __restrict__ off, const int* __restrict__ csr,
    const u16* __restrict__ Wc, const int* __restrict__ flags,
    void* __restrict__ out) {
    __shared__ __align__(16) u16 tile[128 * TPITCH];
    int wid = threadIdx.x >> 6, lane = threadIdx.x & 63;
    int r15 = lane & 15, quad = lane >> 4;
    int rb = blockIdx.x * 128;
    agg_bf16(h1, off, csr, tile, rb, wid, lane);
    __syncthreads();
    int ar0l = wid * 32 + r15, ar1l = ar0l + 16;
    int ar0g = rb + ar0l; if (ar0g > N_NODES - 1) ar0g = N_NODES - 1;
    int ar1g = rb + ar1l; if (ar1g > N_NODES - 1) ar1g = N_NODES - 1;
    f32x4 acc2[2][8] = {};
#pragma unroll
    for (int ks = 0; ks < 4; ks++) {
        int ko = ks * 32 + quad * 8;
        bf16x8 a0t = ldfrag_lds(tile, ar0l, ko);
        bf16x8 a1t = ldfrag_lds(tile, ar1l, ko);
        bf16x8 a0s = ldfrag(h1, ar0g, ko);
        bf16x8 a1s = ldfrag(h1, ar1g, ko);
#pragma unroll
        for (int ct = 0; ct < 8; ct++) {
            bf16x8 bl = ldfrag(Wc + W_W2L, ct * 16 + r15, ko);
            bf16x8 br = ldfrag(Wc + W_W2R, ct * 16 + r15, ko);
            acc2[0][ct] = mfma16(a0t, bl, acc2[0][ct]);
            acc2[0][ct] = mfma16(a0s, br, acc2[0][ct]);
            acc2[1][ct] = mfma16(a1t, bl, acc2[1][ct]);
            acc2[1][ct] = mfma16(a1s, br, acc2[1][ct]);
        }
    }
    __syncthreads();
#pragma unroll
    for (int ct = 0; ct < 8; ct++) {
        int col = ct * 16 + r15;
        float bb = b2f(Wc[W_B2 + col]);
#pragma unroll
        for (int rt = 0; rt < 2; rt++) {
#pragma unroll
            for (int r = 0; r < 4; r++) {
                int lr = wid * 32 + rt * 16 + quad * 4 + r;
                tile[lr * TPITCH + col] = f2b(acc2[rt][ct][r] + bb);
            }
        }
    }
    __syncthreads();
    float pr[2][4] = {};
    float b4f = b2f(Wc[W_B4]);
#pragma unroll
    for (int half = 0; half < 2; half++) {
        f32x4 acc3[2][8] = {};
#pragma unroll
        for (int ks = 0; ks < 4; ks++) {
            int ko = ks * 32 + quad * 8;
            bf16x8 a0 = ldfrag_lds(tile, ar0l, ko);
            bf16x8 a1 = ldfrag_lds(tile, ar1l, ko);
#pragma unroll
            for (int ct = 0; ct < 8; ct++) {
                bf16x8 b = ldfrag(Wc + W_W3, half * 128 + ct * 16 + r15, ko);
                acc3[0][ct] = mfma16(a0, b, acc3[0][ct]);
                acc3[1][ct] = mfma16(a1, b, acc3[1][ct]);
            }
        }
#pragma unroll
        for (int ct = 0; ct < 8; ct++) {
            int col = half * 128 + ct * 16 + r15;
            float bb = b2f(Wc[W_B3 + col]);
            float w4 = b2f(Wc[W_W4 + col]);
#pragma unroll
            for (int rt = 0; rt < 2; rt++)
#pragma unroll
                for (int r = 0; r < 4; r++)
                    pr[rt][r] += fmaxf(acc3[rt][ct][r] + bb, 0.f) * w4;
        }
    }
#pragma unroll
    for (int m = 1; m < 16; m <<= 1)
#pragma unroll
        for (int rt = 0; rt < 2; rt++)
#pragma unroll
            for (int r = 0; r < 4; r++)
                pr[rt][r] += __shfl_xor(pr[rt][r], m, 64);
    if (r15 == 0) {
        int isf = flags[1];
#pragma unroll
        for (int rt = 0; rt < 2; rt++) {
#pragma unroll
            for (int r = 0; r < 4; r++) {
                int row = rb + wid * 32 + rt * 16 + quad * 4 + r;
                if (row < N_NODES) {
                    float v = pr[rt][r] + b4f;
                    if (isf) ((float*)out)[row] = v;
                    else     ((u16*)out)[row] = f2b(v);
                }
            }
        }
    }
}

extern "C" void kernel_launch(void* const* d_in, const int* in_sizes, int n_in,
                              void* d_out, int out_size, void* d_ws, size_t ws_size,
                              hipStream_t stream) {
    const void* x  = d_in[0];
    const int* ei  = (const int*)d_in[1];

    const size_t A = 256;
    const size_t sFlg  = 256;
    const size_t sGcur = 1024;
    const size_t sGh   = (((size_t)NBIN * NPART * 4) + A - 1) & ~(A - 1);
    const size_t sCnt  = (((size_t)N_NODES * 4) + A - 1) & ~(A - 1);
    const size_t sOffN = (((size_t)N_NODES * 4) + A - 1) & ~(A - 1);
    const size_t sWc   = ((WTOT * 2) + A - 1) & ~(A - 1);
    const size_t sCsrB = (((size_t)NBIN * BCAP * 4) + A - 1) & ~(A - 1);
    const size_t sFB   = (((size_t)N_NODES * 128 * 2) + A - 1) & ~(A - 1);
    const size_t sOff  = (((size_t)(N_NODES + 1) * 4) + A - 1) & ~(A - 1);
    const size_t sCsr  = (((size_t)N_EDGES * 4) + A - 1) & ~(A - 1);
    const size_t needB1 = sFlg + sGcur + 2 * sGh + sCnt + sOffN + sWc + sCsrB + 2 * sFB;
    const size_t needB0 = needB1 + sFB;
    const size_t needS  = sFlg + sCnt + sOff + sCsr + sFB;

    char* ws = (char*)d_ws;
    int gconv = (N_NODES + 63) / 64;
    int gagg  = (N_NODES + 3) / 4;

    CvtArgs ca;
    const int srcIdx[10] = {2, 4, 5, 7, 8, 10, 3, 6, 9, 11};
    const int offs[10] = {W_W1L, W_W1R, W_W2L, W_W2R, W_W3, W_W4, W_B1, W_B2, W_B3, W_B4};
    const int ns[10]   = {16384, 16384, 16384, 16384, 32768, 256, 128, 128, 256, 1};
    for (int i = 0; i < 10; i++) { ca.src[i] = d_in[srcIdx[i]]; ca.off[i] = offs[i]; ca.n[i] = ns[i]; }

    if (ws_size >= needB1) {
        bool t0 = ws_size >= needB0;
        int* flags = (int*)ws;
        int* gcur  = (int*)(ws + sFlg);
        int* ghist = (int*)(ws + sFlg + sGcur);
        int* gbase = (int*)(ws + sFlg + sGcur + sGh);
        int* cnt   = (int*)(ws + sFlg + sGcur + 2 * sGh);
        int* offN  = (int*)(ws + sFlg + sGcur + 2 * sGh + sCnt);
        u16* Wc    = (u16*)(ws + sFlg + sGcur + 2 * sGh + sCnt + sOffN);
        u32* csrb  = (u32*)(ws + sFlg + sGcur + 2 * sGh + sCnt + sOffN + sWc);
        u16* B1    = (u16*)(ws + sFlg + sGcur + 2 * sGh + sCnt + sOffN + sWc + sCsrB);
        u16* B2    = B1 + (sFB / 2);
        u32* gbuf  = (u32*)B2;         // dead after k_binB
        u16* xb    = B2 + (sFB / 2);   // T0 only

        k_detects<<<2, 256, 0, stream>>>((const u64*)ei, (const u32*)x, flags);
        k_rhist<<<NPART, 256, 0, stream>>>(ei, ghist, flags);
        k_rscan<<<NBIN, 512, 0, stream>>>(ghist, gbase, gcur);
        k_rscatter<<<NPART, 256, 0, stream>>>(ei, gbase, gbuf, flags);
        k_binB<<<NBIN, 512, 0, stream>>>(gcur, gbuf, csrb, cnt, offN);

        if (t0) {
            k_cvtxw<<<CVX_BLOCKS + (WTOT + 255) / 256, 256, 0, stream>>>(x, xb, ca, Wc, flags);
            k_aggc<<<gagg, 256, 0, stream>>>(xb, cnt, offN, csrb, B1);
            k_conv1f<false><<<gconv, 256, 0, stream>>>(B1, xb, Wc, flags, B2);
        } else {
            k_cvtw<<<(WTOT + 255) / 256, 256, 0, stream>>>(ca, Wc, flags);
            k_aggcx<<<gagg, 256, 0, stream>>>(x, cnt, offN, csrb, flags, B1);
            k_conv1f<true><<<gconv, 256, 0, stream>>>(B1, x, Wc, flags, B2);
        }
        k_aggc<<<gagg, 256, 0, stream>>>(B2, cnt, offN, csrb, B1);
        k_conv2f<<<gconv, 256, 0, stream>>>(B1, B2, Wc, flags, d_out);
    } else if (ws_size >= needS) {
        int* flags = (int*)ws;
        int* cnt   = (int*)(ws + sFlg);
        u16* Wc    = (u16*)(ws + sFlg);
        int* off   = (int*)(ws + sFlg + sCnt);
        int* csr   = (int*)(ws + sFlg + sCnt + sOff);
        u16* h1    = (u16*)(ws + sFlg + sCnt + sOff + sCsr);

        hipMemsetAsync(ws + sFlg, 0, (size_t)N_NODES * 4, stream);
        k_detects<<<2, 256, 0, stream>>>((const u64*)ei, (const u32*)x, flags);
        k_hist<<<N_EDGES / 256, 256, 0, stream>>>(ei, cnt, flags);
        k_scan<<<1, 1024, 0, stream>>>(cnt, off);
        k_csr<<<N_EDGES / 256, 256, 0, stream>>>(ei, cnt, csr, flags);
        k_cvtw<<<(WTOT + 255) / 256, 256, 0, stream>>>(ca, Wc, flags);
        k_conv1<<<(N_NODES + 127) / 128, 256, 0, stream>>>(x, off, csr, Wc, flags, h1);
        k_conv2mlp<<<(N_NODES + 127) / 128, 256, 0, stream>>>(h1, off, csr, Wc, flags, d_out);
    } else {
        k_diag<<<(N_NODES + 255) / 256, 256, 0, stream>>>(
            (u16*)d_out, 2000.0f + (float)(ws_size >> 20));
    }
}